// Round 2
// baseline (3382.795 us; speedup 1.0000x reference)
//
#include <hip/hip_runtime.h>
#include <hip/hip_bf16.h>

#define N_NODES 20000
#define N_EDGES 250000
#define T_WIN   60
#define F_IN    16
#define HID     128
#define G4      512      // 4*HID
#define KTOT    144      // HID + F_IN
#define HEADS   4

// ---------------- ws layout (float offsets) ----------------
#define WCAT_OFF   0            // 144*512 = 73728
#define BIASC_OFF  73728        // 512
#define H_OFF      74240        // 20000*128 = 2,560,000
#define XL_OFF     2634240      // 20000*512 = 10,240,000
#define XR_OFF     12874240     // 10,240,000
#define CNT_OFF    23114240     // 20000 ints
#define CNT2_OFF   23134240     // 20000 ints
#define BASE_OFF   23154240     // 20001 ints
#define SRT_OFF    23174241     // 250000 ints

__device__ __forceinline__ float fsigmoid(float x) { return 1.0f / (1.0f + __expf(-x)); }
__device__ __forceinline__ float ftanh(float x)    { return 2.0f / (1.0f + __expf(-2.0f * x)) - 1.0f; }

// ---------------- pack W_ih/W_hh into Wcat[144][512] (k-major) ----------------
__global__ void pack_kernel(const float* __restrict__ Wih, const float* __restrict__ Whh,
                            const float* __restrict__ bih, const float* __restrict__ bhh,
                            float* __restrict__ Wcat, float* __restrict__ biasc)
{
    int idx = blockIdx.x * 256 + threadIdx.x;
    if (idx < KTOT * G4) {
        int k = idx >> 9;          // 0..143
        int j = idx & 511;         // gate col
        Wcat[idx] = (k < HID) ? Whh[j * HID + k] : Wih[j * F_IN + (k - HID)];
    }
    if (idx < G4) biasc[idx] = bih[idx] + bhh[idx];
}

// ---------------- LSTM: 32 nodes per block, persistent over 60 steps ----------------
#define BM   32
#define ASTR 36   // padded LDS stride for A panel

__global__ __launch_bounds__(256) void lstm_kernel(
    const float* __restrict__ x, const float* __restrict__ Wcat,
    const float* __restrict__ biasc, float* __restrict__ hout)
{
    __shared__ __align__(16) float As[KTOT * ASTR];  // A^T: [k][node], rows 0..127 = h, 128..143 = x_t
    __shared__ __align__(16) float Ws[8 * G4];       // W chunk: [k][512]
    const int tid = threadIdx.x;
    const int tx  = tid & 63;   // col group: cols g*128 + tx*2 + {0,1}
    const int ty  = tid >> 6;   // node group: nodes ty*8 .. +8
    const int n0  = blockIdx.x * BM;

    for (int i = tid; i < KTOT * ASTR; i += 256) As[i] = 0.0f;

    float bje[4][2];
#pragma unroll
    for (int g = 0; g < 4; ++g) {
        bje[g][0] = biasc[g * 128 + tx * 2];
        bje[g][1] = biasc[g * 128 + tx * 2 + 1];
    }
    float cst[8][2];
#pragma unroll
    for (int mi = 0; mi < 8; ++mi) { cst[mi][0] = 0.0f; cst[mi][1] = 0.0f; }

    const int xm = tid >> 3;            // node 0..31
    const int xf = (tid & 7) * 2;       // feature 0,2,..,14
    const float* xbase = x + (size_t)(n0 + xm) * (T_WIN * F_IN) + xf;

    __syncthreads();

    for (int t = 0; t < T_WIN; ++t) {
        // stage x_t into rows 128..143 (h rows already hold h_{t-1})
        float2 xv = *(const float2*)(xbase + t * F_IN);
        As[(HID + xf) * ASTR + xm]     = xv.x;
        As[(HID + xf + 1) * ASTR + xm] = xv.y;

        float acc[8][4][2];
#pragma unroll
        for (int mi = 0; mi < 8; ++mi)
#pragma unroll
            for (int g = 0; g < 4; ++g) {
                acc[mi][g][0] = bje[g][0];
                acc[mi][g][1] = bje[g][1];
            }

        for (int c8 = 0; c8 < KTOT / 8; ++c8) {
            __syncthreads();   // previous chunk's Ws reads done; x/h writes visible
            const float* wsrc = Wcat + c8 * 8 * G4;
#pragma unroll
            for (int q = 0; q < 4; ++q) {
                int fi = tid + q * 256;
                *(float4*)&Ws[fi * 4] = *(const float4*)&wsrc[fi * 4];
            }
            __syncthreads();
#pragma unroll
            for (int k = 0; k < 8; ++k) {
                const float* ar = &As[(c8 * 8 + k) * ASTR + ty * 8];
                float4 a0 = *(const float4*)ar;
                float4 a1 = *(const float4*)(ar + 4);
                float av[8] = {a0.x, a0.y, a0.z, a0.w, a1.x, a1.y, a1.z, a1.w};
                float2 wv[4];
#pragma unroll
                for (int g = 0; g < 4; ++g)
                    wv[g] = *(const float2*)&Ws[k * G4 + g * 128 + tx * 2];
#pragma unroll
                for (int mi = 0; mi < 8; ++mi)
#pragma unroll
                    for (int g = 0; g < 4; ++g) {
                        acc[mi][g][0] = fmaf(av[mi], wv[g].x, acc[mi][g][0]);
                        acc[mi][g][1] = fmaf(av[mi], wv[g].y, acc[mi][g][1]);
                    }
            }
        }
        __syncthreads();   // all A reads done before h rows are overwritten

        // gate nonlinearities + state update; write h_t back into A panel
#pragma unroll
        for (int mi = 0; mi < 8; ++mi)
#pragma unroll
            for (int kk = 0; kk < 2; ++kk) {
                float ig = fsigmoid(acc[mi][0][kk]);
                float fg = fsigmoid(acc[mi][1][kk]);
                float gg = ftanh(acc[mi][2][kk]);
                float og = fsigmoid(acc[mi][3][kk]);
                float cn = fg * cst[mi][kk] + ig * gg;
                cst[mi][kk] = cn;
                As[(tx * 2 + kk) * ASTR + ty * 8 + mi] = og * ftanh(cn);
            }
    }
    __syncthreads();
#pragma unroll
    for (int q = 0; q < 16; ++q) {
        int fi = tid + q * 256;
        int m = fi >> 7;
        int k = fi & 127;
        hout[(size_t)(n0 + m) * HID + k] = As[k * ASTR + m];
    }
}

// ---------------- GEMM2: xl = h@Wl^T + bl ; xr = h@Wr^T + br ----------------
__global__ __launch_bounds__(256) void gemm2_kernel(
    const float* __restrict__ h,
    const float* __restrict__ Wl, const float* __restrict__ bl,
    const float* __restrict__ Wr, const float* __restrict__ br,
    float* __restrict__ xl, float* __restrict__ xr)
{
    __shared__ __align__(16) float AsT[128 * 68];  // [k][node], stride 68
    __shared__ __align__(16) float Ws[16 * 260];   // [k][col],  stride 260
    const int tid = threadIdx.x;
    const int bn = blockIdx.x & 3;   // 4 col-blocks of 256 (xl: 0,1  xr: 2,3)
    const int bm = blockIdx.x >> 2;
    const int n0 = bm * 64;
    const int j0 = bn * 256;
    const float* W    = (j0 < 512) ? Wl : Wr;
    const float* bias = (j0 < 512) ? bl : br;
    float* out        = (j0 < 512) ? xl : xr;
    const int jb = j0 & 511;
    const int txc = tid & 31;  // 8 cols each
    const int tyn = tid >> 5;  // 8 nodes each

    // stage A^T
#pragma unroll
    for (int q = 0; q < 8; ++q) {
        int fi = tid + q * 256;          // float4 index over [64][32]
        int node = fi >> 5, k4 = fi & 31;
        float4 v;
        if (n0 + node < N_NODES) v = *(const float4*)&h[(size_t)(n0 + node) * HID + k4 * 4];
        else { v.x = v.y = v.z = v.w = 0.0f; }
        AsT[(k4 * 4 + 0) * 68 + node] = v.x;
        AsT[(k4 * 4 + 1) * 68 + node] = v.y;
        AsT[(k4 * 4 + 2) * 68 + node] = v.z;
        AsT[(k4 * 4 + 3) * 68 + node] = v.w;
    }

    float b8[8];
#pragma unroll
    for (int ni = 0; ni < 8; ++ni) b8[ni] = bias[jb + txc * 8 + ni];
    float acc[8][8];
#pragma unroll
    for (int mi = 0; mi < 8; ++mi)
#pragma unroll
        for (int ni = 0; ni < 8; ++ni) acc[mi][ni] = b8[ni];

    for (int kc = 0; kc < 8; ++kc) {   // K chunks of 16
        __syncthreads();
#pragma unroll
        for (int q = 0; q < 4; ++q) {
            int idx = tid + q * 256;
            int jj = idx >> 2, kq = idx & 3;
            float4 v = *(const float4*)&W[(size_t)(jb + jj) * HID + kc * 16 + kq * 4];
            Ws[(kq * 4 + 0) * 260 + jj] = v.x;
            Ws[(kq * 4 + 1) * 260 + jj] = v.y;
            Ws[(kq * 4 + 2) * 260 + jj] = v.z;
            Ws[(kq * 4 + 3) * 260 + jj] = v.w;
        }
        __syncthreads();
#pragma unroll
        for (int k = 0; k < 16; ++k) {
            float4 a0 = *(const float4*)&AsT[(kc * 16 + k) * 68 + tyn * 8];
            float4 a1 = *(const float4*)&AsT[(kc * 16 + k) * 68 + tyn * 8 + 4];
            float4 w0 = *(const float4*)&Ws[k * 260 + txc * 8];
            float4 w1 = *(const float4*)&Ws[k * 260 + txc * 8 + 4];
            float av[8] = {a0.x, a0.y, a0.z, a0.w, a1.x, a1.y, a1.z, a1.w};
            float wv[8] = {w0.x, w0.y, w0.z, w0.w, w1.x, w1.y, w1.z, w1.w};
#pragma unroll
            for (int mi = 0; mi < 8; ++mi)
#pragma unroll
                for (int ni = 0; ni < 8; ++ni)
                    acc[mi][ni] = fmaf(av[mi], wv[ni], acc[mi][ni]);
        }
    }

#pragma unroll
    for (int mi = 0; mi < 8; ++mi) {
        int n = n0 + tyn * 8 + mi;
        if (n < N_NODES) {
            float4 s0 = {acc[mi][0], acc[mi][1], acc[mi][2], acc[mi][3]};
            float4 s1 = {acc[mi][4], acc[mi][5], acc[mi][6], acc[mi][7]};
            *(float4*)&out[(size_t)n * G4 + jb + txc * 8]     = s0;
            *(float4*)&out[(size_t)n * G4 + jb + txc * 8 + 4] = s1;
        }
    }
}

// ---------------- edge sort (counting sort by dst) ----------------
// NOTE: harness delivers integer inputs as int32 (NOT int64) — cast const int*.
__global__ void count_kernel(const int* __restrict__ ei, int* __restrict__ cnt)
{
    int e = blockIdx.x * 256 + threadIdx.x;
    if (e < N_EDGES) {
        int dst = ei[N_EDGES + e];
        if (dst >= 0 && dst < N_NODES) atomicAdd(&cnt[dst], 1);
    }
}

__global__ void scan_kernel(const int* __restrict__ cnt, int* __restrict__ base)
{
    __shared__ int ps[256];
    const int tid = threadIdx.x;
    const int CH = (N_NODES + 255) / 256;  // 79
    int s = 0;
    for (int i = 0; i < CH; ++i) {
        int idx = tid * CH + i;
        if (idx < N_NODES) s += cnt[idx];
    }
    ps[tid] = s;
    __syncthreads();
    for (int off = 1; off < 256; off <<= 1) {
        int v = (tid >= off) ? ps[tid - off] : 0;
        __syncthreads();
        ps[tid] += v;
        __syncthreads();
    }
    int run = (tid > 0) ? ps[tid - 1] : 0;
    for (int i = 0; i < CH; ++i) {
        int idx = tid * CH + i;
        if (idx < N_NODES) { base[idx] = run; run += cnt[idx]; }
    }
    if (tid == 255) base[N_NODES] = ps[255];
}

__global__ void scatter_kernel(const int* __restrict__ ei, const int* __restrict__ base,
                               int* __restrict__ cnt2, int* __restrict__ srt)
{
    int e = blockIdx.x * 256 + threadIdx.x;
    if (e < N_EDGES) {
        int dst = ei[N_EDGES + e];
        int src = ei[e];
        if (dst >= 0 && dst < N_NODES) {
            int pos = base[dst] + atomicAdd(&cnt2[dst], 1);
            srt[pos] = src;
        }
    }
}

// ---------------- GATv2 aggregate: one wave per dst, online softmax ----------------
__global__ __launch_bounds__(256) void gat_kernel(
    const float* __restrict__ xl, const float* __restrict__ xr,
    const float* __restrict__ att, const float* __restrict__ gbias,
    const float* __restrict__ Wp, const float* __restrict__ bp,
    const int* __restrict__ base, const int* __restrict__ srt,
    float* __restrict__ out)
{
    const int wave = threadIdx.x >> 6;
    const int lane = threadIdx.x & 63;
    const int dst = blockIdx.x * 4 + wave;
    if (dst >= N_NODES) return;

    // lane covers global cols [lane*8, lane*8+8) = head (lane>>4), c0 = (lane&15)*8
    float4 xr0 = *(const float4*)&xr[(size_t)dst * G4 + lane * 8];
    float4 xr1 = *(const float4*)&xr[(size_t)dst * G4 + lane * 8 + 4];
    float xrv[8] = {xr0.x, xr0.y, xr0.z, xr0.w, xr1.x, xr1.y, xr1.z, xr1.w};
    float4 at0 = *(const float4*)&att[lane * 8];
    float4 at1 = *(const float4*)&att[lane * 8 + 4];
    float atv[8] = {at0.x, at0.y, at0.z, at0.w, at1.x, at1.y, at1.z, at1.w};

    float m = -INFINITY, d = 0.0f;
    float acc[8];
#pragma unroll
    for (int i = 0; i < 8; ++i) acc[i] = 0.0f;

    const int b0 = base[dst], b1 = base[dst + 1];
    for (int idx = b0; idx <= b1; ++idx) {       // idx == b1 -> self loop
        int src = (idx < b1) ? srt[idx] : dst;
        float4 v0 = *(const float4*)&xl[(size_t)src * G4 + lane * 8];
        float4 v1 = *(const float4*)&xl[(size_t)src * G4 + lane * 8 + 4];
        float xv[8] = {v0.x, v0.y, v0.z, v0.w, v1.x, v1.y, v1.z, v1.w};
        float p = 0.0f;
#pragma unroll
        for (int i = 0; i < 8; ++i) {
            float e = xv[i] + xrv[i];
            e = (e > 0.0f) ? e : 0.2f * e;       // LeakyReLU(0.2)
            p = fmaf(atv[i], e, p);
        }
        // reduce over the 16 lanes of this head
        p += __shfl_xor(p, 1);
        p += __shfl_xor(p, 2);
        p += __shfl_xor(p, 4);
        p += __shfl_xor(p, 8);
        // online softmax update
        float mn = fmaxf(m, p);
        float scale = __expf(m - mn);
        float al = __expf(p - mn);
        d = d * scale + al;
#pragma unroll
        for (int i = 0; i < 8; ++i) acc[i] = fmaf(al, xv[i], acc[i] * scale);
        m = mn;
    }

    float inv = 1.0f / d;
    float o[8];
#pragma unroll
    for (int i = 0; i < 8; ++i) o[i] = acc[i] * inv;
    // sum over heads (lanes differing in bits 4,5 hold same c, different head)
#pragma unroll
    for (int i = 0; i < 8; ++i) {
        o[i] += __shfl_xor(o[i], 16);
        o[i] += __shfl_xor(o[i], 32);
    }
    const int c0 = (lane & 15) * 8;
    float psum = 0.0f;
#pragma unroll
    for (int i = 0; i < 8; ++i) {
        float s = 0.25f * o[i] + gbias[c0 + i];
        s = (s > 0.0f) ? s : (__expf(s) - 1.0f);   // ELU
        psum = fmaf(s, Wp[c0 + i], psum);
    }
    psum += __shfl_xor(psum, 1);
    psum += __shfl_xor(psum, 2);
    psum += __shfl_xor(psum, 4);
    psum += __shfl_xor(psum, 8);
    if (lane == 0) out[dst] = psum + bp[0];
}

// ---------------- launch ----------------
extern "C" void kernel_launch(void* const* d_in, const int* in_sizes, int n_in,
                              void* d_out, int out_size, void* d_ws, size_t ws_size,
                              hipStream_t stream)
{
    const float* x        = (const float*)d_in[0];
    const int* ei         = (const int*)d_in[1];     // int32 per harness contract
    const float* Wih      = (const float*)d_in[2];
    const float* Whh      = (const float*)d_in[3];
    const float* bih      = (const float*)d_in[4];
    const float* bhh      = (const float*)d_in[5];
    const float* Wl       = (const float*)d_in[6];
    const float* bl       = (const float*)d_in[7];
    const float* Wr       = (const float*)d_in[8];
    const float* br       = (const float*)d_in[9];
    const float* att      = (const float*)d_in[10];
    const float* gbias    = (const float*)d_in[11];
    const float* Wp       = (const float*)d_in[12];
    const float* bp       = (const float*)d_in[13];
    float* out            = (float*)d_out;

    float* ws   = (float*)d_ws;
    float* Wcat = ws + WCAT_OFF;
    float* bsc  = ws + BIASC_OFF;
    float* h    = ws + H_OFF;
    float* xl   = ws + XL_OFF;
    float* xr   = ws + XR_OFF;
    int* cnt    = (int*)(ws + CNT_OFF);
    int* cnt2   = (int*)(ws + CNT2_OFF);
    int* base   = (int*)(ws + BASE_OFF);
    int* srt    = (int*)(ws + SRT_OFF);

    hipMemsetAsync(cnt, 0, 2 * N_NODES * sizeof(int), stream);  // cnt + cnt2 (contiguous)

    pack_kernel<<<(KTOT * G4 + 255) / 256, 256, 0, stream>>>(Wih, Whh, bih, bhh, Wcat, bsc);
    count_kernel<<<(N_EDGES + 255) / 256, 256, 0, stream>>>(ei, cnt);
    scan_kernel<<<1, 256, 0, stream>>>(cnt, base);
    scatter_kernel<<<(N_EDGES + 255) / 256, 256, 0, stream>>>(ei, base, cnt2, srt);

    lstm_kernel<<<N_NODES / BM, 256, 0, stream>>>(x, Wcat, bsc, h);
    gemm2_kernel<<<((N_NODES + 63) / 64) * 4, 256, 0, stream>>>(h, Wl, bl, Wr, br, xl, xr);
    gat_kernel<<<(N_NODES + 3) / 4, 256, 0, stream>>>(xl, xr, att, gbias, Wp, bp, base, srt, out);
}

// Round 3
// 813.956 us; speedup vs baseline: 4.1560x; 4.1560x over previous
//
#include <hip/hip_runtime.h>
#include <hip/hip_bf16.h>

#define N_NODES 20000
#define N_EDGES 250000
#define T_WIN   60
#define F_IN    16
#define HID     128
#define G4      512      // 4*HID
#define HEADS   4

// ---------------- ws layout (float offsets) ----------------
#define WPK_OFF    0            // 81920 ushort = 40960 floats (MFMA B-frag packed W)
#define BIASC_OFF  73728        // 512
#define H_OFF      74240        // 20000*128 = 2,560,000
#define XL_OFF     2634240      // 20000*512 = 10,240,000
#define XR_OFF     12874240     // 10,240,000
#define CNT_OFF    23114240     // 20000 ints
#define CNT2_OFF   23134240     // 20000 ints
#define BASE_OFF   23154240     // 20001 ints
#define SRT_OFF    23174241     // 250000 ints

typedef __attribute__((ext_vector_type(8))) short short8;
typedef __attribute__((ext_vector_type(4))) float f32x4;
typedef __attribute__((ext_vector_type(4))) unsigned short ushortx4;

__device__ __forceinline__ float fsigmoid(float x) { return 1.0f / (1.0f + __expf(-x)); }
__device__ __forceinline__ float ftanh(float x)    { return 2.0f / (1.0f + __expf(-2.0f * x)) - 1.0f; }

__device__ __forceinline__ unsigned short f2bf(float f) {
    unsigned u = __float_as_uint(f);
    u += 0x7FFFu + ((u >> 16) & 1u);   // RNE
    return (unsigned short)(u >> 16);
}

// ---------------- pack W into MFMA B-fragment layout ----------------
// Wpk index = (((g*8+ht)*5+kt)*64 + lane)*8 + i
// element: k = kt*32 + (lane>>4)*8 + i ; col = g*128 + ht*16 + (lane&15)
// B[k][col] = k<128 ? Whh[col][k] : (k<144 ? Wih[col][k-128] : 0)
__global__ void pack_w_kernel(const float* __restrict__ Wih, const float* __restrict__ Whh,
                              const float* __restrict__ bih, const float* __restrict__ bhh,
                              unsigned short* __restrict__ wpk, float* __restrict__ biasc)
{
    int idx = blockIdx.x * 256 + threadIdx.x;
    if (idx < 81920) {
        int i  = idx & 7;
        int l  = (idx >> 3) & 63;
        int r  = idx >> 9;
        int kt = r % 5;
        int gh = r / 5;
        int ht = gh & 7;
        int g  = gh >> 3;
        int k   = kt * 32 + (l >> 4) * 8 + i;
        int col = g * 128 + ht * 16 + (l & 15);
        float v = 0.0f;
        if (k < 128)      v = Whh[col * 128 + k];
        else if (k < 144) v = Wih[col * 16 + (k - 128)];
        wpk[idx] = f2bf(v);
    }
    if (idx < G4) biasc[idx] = bih[idx] + bhh[idx];
}

// ---------------- LSTM: MFMA bf16, 80 nodes/block, 250 blocks ----------------
// LDS A-panel: [80 nodes][384 bytes]  (k*2 byte offset, XOR-swizzled by (node&7)<<4)
//   k 0..127 = h (bf16), k 128..143 = x_t (bf16), k 144..159 zero pad, rest unused
#define BMM  80
#define ASTR 384

__global__ __launch_bounds__(512) void lstm_mfma_kernel(
    const float* __restrict__ x, const unsigned short* __restrict__ wpk,
    const float* __restrict__ biasc, float* __restrict__ hout)
{
    __shared__ __align__(16) unsigned char Abuf[BMM * ASTR];
    const int tid  = threadIdx.x;
    const int wave = tid >> 6;
    const int lane = tid & 63;
    const int n0   = blockIdx.x * BMM;

    // zero the whole panel (h0 = 0, pad = 0)
    {
        f32x4 z = {0.0f, 0.0f, 0.0f, 0.0f};
        for (int i = tid; i < BMM * ASTR / 16; i += 512)
            *(f32x4*)&Abuf[i * 16] = z;
    }

    // persistent B-fragments: wave w owns hid cols [w*16, w*16+16) for all 4 gates
    short8 wf[4][5];
#pragma unroll
    for (int g = 0; g < 4; ++g)
#pragma unroll
        for (int kt = 0; kt < 5; ++kt)
            wf[g][kt] = *(const short8*)&wpk[((((g * 8 + wave) * 5) + kt) * 64 + lane) * 8];

    float bias[4];
#pragma unroll
    for (int g = 0; g < 4; ++g) bias[g] = biasc[g * 128 + wave * 16 + (lane & 15)];

    float c[5][4];
#pragma unroll
    for (int mt = 0; mt < 5; ++mt)
#pragma unroll
        for (int r = 0; r < 4; ++r) c[mt][r] = 0.0f;

    const int xnode = tid >> 2;   // 0..127 (only <80 active)
    const int xq    = tid & 3;
    const int colw  = wave * 16 + (lane & 15);

    __syncthreads();

#pragma unroll 1
    for (int t = 0; t < T_WIN; ++t) {
        // stage x_t (bf16) into k rows 128..143
        if (tid < BMM * 4) {
            const float* xs = &x[(size_t)(n0 + xnode) * (T_WIN * F_IN) + t * F_IN + xq * 4];
            float4 v = *(const float4*)xs;
            ushortx4 b;
            b.x = f2bf(v.x); b.y = f2bf(v.y); b.z = f2bf(v.z); b.w = f2bf(v.w);
            int off = (256 + xq * 8) ^ ((xnode & 7) << 4);
            *(ushortx4*)&Abuf[xnode * ASTR + off] = b;
        }
        __syncthreads();   // x_t + h_{t-1} visible

        f32x4 acc[5][4];
#pragma unroll
        for (int mt = 0; mt < 5; ++mt)
#pragma unroll
            for (int g = 0; g < 4; ++g) {
                f32x4 a = {bias[g], bias[g], bias[g], bias[g]};
                acc[mt][g] = a;
            }

#pragma unroll
        for (int kt = 0; kt < 5; ++kt) {
            short8 af[5];
            const int koff = (kt * 32 + (lane >> 4) * 8) * 2;
#pragma unroll
            for (int mt = 0; mt < 5; ++mt) {
                int row = mt * 16 + (lane & 15);
                af[mt] = *(const short8*)&Abuf[row * ASTR + (koff ^ ((row & 7) << 4))];
            }
#pragma unroll
            for (int mt = 0; mt < 5; ++mt)
#pragma unroll
                for (int g = 0; g < 4; ++g)
                    acc[mt][g] = __builtin_amdgcn_mfma_f32_16x16x32_bf16(
                        af[mt], wf[g][kt], acc[mt][g], 0, 0, 0);
        }
        __syncthreads();   // all A-panel reads done before h overwrite

        // gates -> c,h (fp32, per-lane); write h_t back (bf16) or final h (fp32)
#pragma unroll
        for (int mt = 0; mt < 5; ++mt)
#pragma unroll
            for (int r = 0; r < 4; ++r) {
                float ig = fsigmoid(acc[mt][0][r]);
                float fg = fsigmoid(acc[mt][1][r]);
                float gg = ftanh(acc[mt][2][r]);
                float og = fsigmoid(acc[mt][3][r]);
                float cn = fg * c[mt][r] + ig * gg;
                c[mt][r] = cn;
                float h = og * ftanh(cn);
                int node = mt * 16 + (lane >> 4) * 4 + r;
                if (t < T_WIN - 1) {
                    *(unsigned short*)&Abuf[node * ASTR + ((colw * 2) ^ ((node & 7) << 4))] = f2bf(h);
                } else {
                    hout[(size_t)(n0 + node) * HID + colw] = h;
                }
            }
    }
}

// ---------------- GEMM2: xl = h@Wl^T + bl ; xr = h@Wr^T + br ----------------
__global__ __launch_bounds__(256) void gemm2_kernel(
    const float* __restrict__ h,
    const float* __restrict__ Wl, const float* __restrict__ bl,
    const float* __restrict__ Wr, const float* __restrict__ br,
    float* __restrict__ xl, float* __restrict__ xr)
{
    __shared__ __align__(16) float AsT[128 * 68];  // [k][node], stride 68
    __shared__ __align__(16) float Ws[16 * 260];   // [k][col],  stride 260
    const int tid = threadIdx.x;
    const int bn = blockIdx.x & 3;
    const int bm = blockIdx.x >> 2;
    const int n0 = bm * 64;
    const int j0 = bn * 256;
    const float* W    = (j0 < 512) ? Wl : Wr;
    const float* bias = (j0 < 512) ? bl : br;
    float* out        = (j0 < 512) ? xl : xr;
    const int jb = j0 & 511;
    const int txc = tid & 31;
    const int tyn = tid >> 5;

#pragma unroll
    for (int q = 0; q < 8; ++q) {
        int fi = tid + q * 256;
        int node = fi >> 5, k4 = fi & 31;
        float4 v;
        if (n0 + node < N_NODES) v = *(const float4*)&h[(size_t)(n0 + node) * HID + k4 * 4];
        else { v.x = v.y = v.z = v.w = 0.0f; }
        AsT[(k4 * 4 + 0) * 68 + node] = v.x;
        AsT[(k4 * 4 + 1) * 68 + node] = v.y;
        AsT[(k4 * 4 + 2) * 68 + node] = v.z;
        AsT[(k4 * 4 + 3) * 68 + node] = v.w;
    }

    float b8[8];
#pragma unroll
    for (int ni = 0; ni < 8; ++ni) b8[ni] = bias[jb + txc * 8 + ni];
    float acc[8][8];
#pragma unroll
    for (int mi = 0; mi < 8; ++mi)
#pragma unroll
        for (int ni = 0; ni < 8; ++ni) acc[mi][ni] = b8[ni];

    for (int kc = 0; kc < 8; ++kc) {
        __syncthreads();
#pragma unroll
        for (int q = 0; q < 4; ++q) {
            int idx = tid + q * 256;
            int jj = idx >> 2, kq = idx & 3;
            float4 v = *(const float4*)&W[(size_t)(jb + jj) * HID + kc * 16 + kq * 4];
            Ws[(kq * 4 + 0) * 260 + jj] = v.x;
            Ws[(kq * 4 + 1) * 260 + jj] = v.y;
            Ws[(kq * 4 + 2) * 260 + jj] = v.z;
            Ws[(kq * 4 + 3) * 260 + jj] = v.w;
        }
        __syncthreads();
#pragma unroll
        for (int k = 0; k < 16; ++k) {
            float4 a0 = *(const float4*)&AsT[(kc * 16 + k) * 68 + tyn * 8];
            float4 a1 = *(const float4*)&AsT[(kc * 16 + k) * 68 + tyn * 8 + 4];
            float4 w0 = *(const float4*)&Ws[k * 260 + txc * 8];
            float4 w1 = *(const float4*)&Ws[k * 260 + txc * 8 + 4];
            float av[8] = {a0.x, a0.y, a0.z, a0.w, a1.x, a1.y, a1.z, a1.w};
            float wv[8] = {w0.x, w0.y, w0.z, w0.w, w1.x, w1.y, w1.z, w1.w};
#pragma unroll
            for (int mi = 0; mi < 8; ++mi)
#pragma unroll
                for (int ni = 0; ni < 8; ++ni)
                    acc[mi][ni] = fmaf(av[mi], wv[ni], acc[mi][ni]);
        }
    }

#pragma unroll
    for (int mi = 0; mi < 8; ++mi) {
        int n = n0 + tyn * 8 + mi;
        if (n < N_NODES) {
            float4 s0 = {acc[mi][0], acc[mi][1], acc[mi][2], acc[mi][3]};
            float4 s1 = {acc[mi][4], acc[mi][5], acc[mi][6], acc[mi][7]};
            *(float4*)&out[(size_t)n * G4 + jb + txc * 8]     = s0;
            *(float4*)&out[(size_t)n * G4 + jb + txc * 8 + 4] = s1;
        }
    }
}

// ---------------- edge sort (counting sort by dst) ----------------
__global__ void count_kernel(const int* __restrict__ ei, int* __restrict__ cnt)
{
    int e = blockIdx.x * 256 + threadIdx.x;
    if (e < N_EDGES) {
        int dst = ei[N_EDGES + e];
        if (dst >= 0 && dst < N_NODES) atomicAdd(&cnt[dst], 1);
    }
}

__global__ void scan_kernel(const int* __restrict__ cnt, int* __restrict__ base)
{
    __shared__ int ps[256];
    const int tid = threadIdx.x;
    const int CH = (N_NODES + 255) / 256;
    int s = 0;
    for (int i = 0; i < CH; ++i) {
        int idx = tid * CH + i;
        if (idx < N_NODES) s += cnt[idx];
    }
    ps[tid] = s;
    __syncthreads();
    for (int off = 1; off < 256; off <<= 1) {
        int v = (tid >= off) ? ps[tid - off] : 0;
        __syncthreads();
        ps[tid] += v;
        __syncthreads();
    }
    int run = (tid > 0) ? ps[tid - 1] : 0;
    for (int i = 0; i < CH; ++i) {
        int idx = tid * CH + i;
        if (idx < N_NODES) { base[idx] = run; run += cnt[idx]; }
    }
    if (tid == 255) base[N_NODES] = ps[255];
}

__global__ void scatter_kernel(const int* __restrict__ ei, const int* __restrict__ base,
                               int* __restrict__ cnt2, int* __restrict__ srt)
{
    int e = blockIdx.x * 256 + threadIdx.x;
    if (e < N_EDGES) {
        int dst = ei[N_EDGES + e];
        int src = ei[e];
        if (dst >= 0 && dst < N_NODES) {
            int pos = base[dst] + atomicAdd(&cnt2[dst], 1);
            srt[pos] = src;
        }
    }
}

// ---------------- GATv2 aggregate: one wave per dst, online softmax ----------------
__global__ __launch_bounds__(256) void gat_kernel(
    const float* __restrict__ xl, const float* __restrict__ xr,
    const float* __restrict__ att, const float* __restrict__ gbias,
    const float* __restrict__ Wp, const float* __restrict__ bp,
    const int* __restrict__ base, const int* __restrict__ srt,
    float* __restrict__ out)
{
    const int wave = threadIdx.x >> 6;
    const int lane = threadIdx.x & 63;
    const int dst = blockIdx.x * 4 + wave;
    if (dst >= N_NODES) return;

    float4 xr0 = *(const float4*)&xr[(size_t)dst * G4 + lane * 8];
    float4 xr1 = *(const float4*)&xr[(size_t)dst * G4 + lane * 8 + 4];
    float xrv[8] = {xr0.x, xr0.y, xr0.z, xr0.w, xr1.x, xr1.y, xr1.z, xr1.w};
    float4 at0 = *(const float4*)&att[lane * 8];
    float4 at1 = *(const float4*)&att[lane * 8 + 4];
    float atv[8] = {at0.x, at0.y, at0.z, at0.w, at1.x, at1.y, at1.z, at1.w};

    float m = -INFINITY, d = 0.0f;
    float acc[8];
#pragma unroll
    for (int i = 0; i < 8; ++i) acc[i] = 0.0f;

    const int b0 = base[dst], b1 = base[dst + 1];
    for (int idx = b0; idx <= b1; ++idx) {
        int src = (idx < b1) ? srt[idx] : dst;
        float4 v0 = *(const float4*)&xl[(size_t)src * G4 + lane * 8];
        float4 v1 = *(const float4*)&xl[(size_t)src * G4 + lane * 8 + 4];
        float xv[8] = {v0.x, v0.y, v0.z, v0.w, v1.x, v1.y, v1.z, v1.w};
        float p = 0.0f;
#pragma unroll
        for (int i = 0; i < 8; ++i) {
            float e = xv[i] + xrv[i];
            e = (e > 0.0f) ? e : 0.2f * e;
            p = fmaf(atv[i], e, p);
        }
        p += __shfl_xor(p, 1);
        p += __shfl_xor(p, 2);
        p += __shfl_xor(p, 4);
        p += __shfl_xor(p, 8);
        float mn = fmaxf(m, p);
        float scale = __expf(m - mn);
        float al = __expf(p - mn);
        d = d * scale + al;
#pragma unroll
        for (int i = 0; i < 8; ++i) acc[i] = fmaf(al, xv[i], acc[i] * scale);
        m = mn;
    }

    float inv = 1.0f / d;
    float o[8];
#pragma unroll
    for (int i = 0; i < 8; ++i) o[i] = acc[i] * inv;
#pragma unroll
    for (int i = 0; i < 8; ++i) {
        o[i] += __shfl_xor(o[i], 16);
        o[i] += __shfl_xor(o[i], 32);
    }
    const int c0 = (lane & 15) * 8;
    float psum = 0.0f;
#pragma unroll
    for (int i = 0; i < 8; ++i) {
        float s = 0.25f * o[i] + gbias[c0 + i];
        s = (s > 0.0f) ? s : (__expf(s) - 1.0f);
        psum = fmaf(s, Wp[c0 + i], psum);
    }
    psum += __shfl_xor(psum, 1);
    psum += __shfl_xor(psum, 2);
    psum += __shfl_xor(psum, 4);
    psum += __shfl_xor(psum, 8);
    if (lane == 0) out[dst] = psum + bp[0];
}

// ---------------- launch ----------------
extern "C" void kernel_launch(void* const* d_in, const int* in_sizes, int n_in,
                              void* d_out, int out_size, void* d_ws, size_t ws_size,
                              hipStream_t stream)
{
    const float* x        = (const float*)d_in[0];
    const int* ei         = (const int*)d_in[1];     // int32 per harness contract
    const float* Wih      = (const float*)d_in[2];
    const float* Whh      = (const float*)d_in[3];
    const float* bih      = (const float*)d_in[4];
    const float* bhh      = (const float*)d_in[5];
    const float* Wl       = (const float*)d_in[6];
    const float* bl       = (const float*)d_in[7];
    const float* Wr       = (const float*)d_in[8];
    const float* br       = (const float*)d_in[9];
    const float* att      = (const float*)d_in[10];
    const float* gbias    = (const float*)d_in[11];
    const float* Wp       = (const float*)d_in[12];
    const float* bp       = (const float*)d_in[13];
    float* out            = (float*)d_out;

    float* ws            = (float*)d_ws;
    unsigned short* wpk  = (unsigned short*)(ws + WPK_OFF);
    float* bsc  = ws + BIASC_OFF;
    float* h    = ws + H_OFF;
    float* xl   = ws + XL_OFF;
    float* xr   = ws + XR_OFF;
    int* cnt    = (int*)(ws + CNT_OFF);
    int* cnt2   = (int*)(ws + CNT2_OFF);
    int* base   = (int*)(ws + BASE_OFF);
    int* srt    = (int*)(ws + SRT_OFF);

    hipMemsetAsync(cnt, 0, 2 * N_NODES * sizeof(int), stream);

    pack_w_kernel<<<320, 256, 0, stream>>>(Wih, Whh, bih, bhh, wpk, bsc);
    count_kernel<<<(N_EDGES + 255) / 256, 256, 0, stream>>>(ei, cnt);
    scan_kernel<<<1, 256, 0, stream>>>(cnt, base);
    scatter_kernel<<<(N_EDGES + 255) / 256, 256, 0, stream>>>(ei, base, cnt2, srt);

    lstm_mfma_kernel<<<N_NODES / BMM, 512, 0, stream>>>(x, wpk, bsc, h);
    gemm2_kernel<<<((N_NODES + 63) / 64) * 4, 256, 0, stream>>>(h, Wl, bl, Wr, br, xl, xr);
    gat_kernel<<<(N_NODES + 3) / 4, 256, 0, stream>>>(xl, xr, att, gbias, Wp, bp, base, srt, out);
}

// Round 4
// 673.795 us; speedup vs baseline: 5.0205x; 1.2080x over previous
//
#include <hip/hip_runtime.h>
#include <hip/hip_bf16.h>

#define N_NODES 20000
#define N_EDGES 250000
#define T_WIN   60
#define F_IN    16
#define HID     128
#define G4      512      // 4*HID
#define HEADS   4

// ---------------- ws layout (float offsets) ----------------
#define WPK_OFF    0            // 81920 ushort = 40960 floats (MFMA B-frag packed W)
#define BIASC_OFF  73728        // 512
#define H_OFF      74240        // 20000*128 = 2,560,000
#define XL_OFF     2634240      // 20000*512 = 10,240,000
#define XR_OFF     12874240     // 10,240,000
#define CNT_OFF    23114240     // 20000 ints
#define CNT2_OFF   23134240     // 20000 ints
#define BASE_OFF   23154240     // 20001 ints
#define SRT_OFF    23174241     // 250000 ints

typedef __attribute__((ext_vector_type(8))) short short8;
typedef __attribute__((ext_vector_type(4))) float f32x4;
typedef __attribute__((ext_vector_type(4))) unsigned short ushortx4;

// fast activations: v_rcp_f32 (rel err ~2^-22) instead of IEEE divide
__device__ __forceinline__ float fsigmoid(float x) {
    return __builtin_amdgcn_rcpf(1.0f + __expf(-x));
}
__device__ __forceinline__ float ftanh(float x) {
    return fmaf(2.0f, __builtin_amdgcn_rcpf(1.0f + __expf(-2.0f * x)), -1.0f);
}

__device__ __forceinline__ unsigned short f2bf(float f) {
    unsigned u = __float_as_uint(f);
    u += 0x7FFFu + ((u >> 16) & 1u);   // RNE
    return (unsigned short)(u >> 16);
}

// ---------------- pack W into MFMA B-fragment layout ----------------
// Wpk index = (((g*8+ht)*5+kt)*64 + lane)*8 + i
// element: k = kt*32 + (lane>>4)*8 + i ; col = g*128 + ht*16 + (lane&15)
// B[k][col] = k<128 ? Whh[col][k] : (k<144 ? Wih[col][k-128] : 0)
__global__ void pack_w_kernel(const float* __restrict__ Wih, const float* __restrict__ Whh,
                              const float* __restrict__ bih, const float* __restrict__ bhh,
                              unsigned short* __restrict__ wpk, float* __restrict__ biasc)
{
    int idx = blockIdx.x * 256 + threadIdx.x;
    if (idx < 81920) {
        int i  = idx & 7;
        int l  = (idx >> 3) & 63;
        int r  = idx >> 9;
        int kt = r % 5;
        int gh = r / 5;
        int ht = gh & 7;
        int g  = gh >> 3;
        int k   = kt * 32 + (l >> 4) * 8 + i;
        int col = g * 128 + ht * 16 + (l & 15);
        float v = 0.0f;
        if (k < 128)      v = Whh[col * 128 + k];
        else if (k < 144) v = Wih[col * 16 + (k - 128)];
        wpk[idx] = f2bf(v);
    }
    if (idx < G4) biasc[idx] = bih[idx] + bhh[idx];
}

// ---------------- LSTM: MFMA bf16, 80 nodes/block, double-buffered, 1 barrier/step ----------------
// LDS A-panels: 2 x [80 nodes][384 bytes] (k*2 byte offset, XOR-swizzled by (node&7)<<4)
//   k 0..127 = h (bf16), k 128..143 = x_t (bf16), k 144..159 zero pad
#define BMM  80
#define ASTR 384

__global__ __launch_bounds__(512) void lstm_mfma_kernel(
    const float* __restrict__ x, const unsigned short* __restrict__ wpk,
    const float* __restrict__ biasc, float* __restrict__ hout)
{
    __shared__ __align__(16) unsigned char Abuf[2][BMM * ASTR];
    const int tid  = threadIdx.x;
    const int wave = tid >> 6;
    const int lane = tid & 63;
    const int n0   = blockIdx.x * BMM;

    // zero both panels (h0 = 0, pad = 0)
    {
        f32x4 z = {0.0f, 0.0f, 0.0f, 0.0f};
        unsigned char* ab = &Abuf[0][0];
        for (int i = tid; i < 2 * BMM * ASTR / 16; i += 512)
            *(f32x4*)&ab[i * 16] = z;
    }

    // persistent B-fragments: wave w owns hid cols [w*16, w*16+16) for all 4 gates
    short8 wf[4][5];
#pragma unroll
    for (int g = 0; g < 4; ++g)
#pragma unroll
        for (int kt = 0; kt < 5; ++kt)
            wf[g][kt] = *(const short8*)&wpk[((((g * 8 + wave) * 5) + kt) * 64 + lane) * 8];

    float bias[4];
#pragma unroll
    for (int g = 0; g < 4; ++g) bias[g] = biasc[g * 128 + wave * 16 + (lane & 15)];

    float c[5][4];
#pragma unroll
    for (int mt = 0; mt < 5; ++mt)
#pragma unroll
        for (int r = 0; r < 4; ++r) c[mt][r] = 0.0f;

    const int  xnode   = tid >> 2;          // 0..127 (only <80 active)
    const int  xq      = tid & 3;
    const bool xactive = (tid < BMM * 4);   // 320 threads stage x
    const int  xoff    = (256 + xq * 8) ^ ((xnode & 7) << 4);
    const int  colw    = wave * 16 + (lane & 15);
    const float* xptr  = &x[(size_t)(n0 + xnode) * (T_WIN * F_IN) + xq * 4];

    __syncthreads();   // zeroing complete before x_0 staging

    // stage x_0 into panel 0
    if (xactive) {
        float4 v = *(const float4*)xptr;
        ushortx4 b;
        b.x = f2bf(v.x); b.y = f2bf(v.y); b.z = f2bf(v.z); b.w = f2bf(v.w);
        *(ushortx4*)&Abuf[0][xnode * ASTR + xoff] = b;
    }
    __syncthreads();

#pragma unroll 2
    for (int t = 0; t < T_WIN; ++t) {
        const int cur = t & 1;
        const int nxt = cur ^ 1;

        // prefetch x_{t+1} early so HBM latency hides under MFMA
        float4 xv = {0.0f, 0.0f, 0.0f, 0.0f};
        if (xactive && t + 1 < T_WIN) xv = *(const float4*)(xptr + (t + 1) * F_IN);

        f32x4 acc[5][4];
#pragma unroll
        for (int mt = 0; mt < 5; ++mt)
#pragma unroll
            for (int g = 0; g < 4; ++g) {
                f32x4 a = {bias[g], bias[g], bias[g], bias[g]};
                acc[mt][g] = a;
            }

#pragma unroll
        for (int kt = 0; kt < 5; ++kt) {
            short8 af[5];
            const int koff = (kt * 32 + (lane >> 4) * 8) * 2;
#pragma unroll
            for (int mt = 0; mt < 5; ++mt) {
                int row = mt * 16 + (lane & 15);
                af[mt] = *(const short8*)&Abuf[cur][row * ASTR + (koff ^ ((row & 7) << 4))];
            }
#pragma unroll
            for (int mt = 0; mt < 5; ++mt)
#pragma unroll
                for (int g = 0; g < 4; ++g)
                    acc[mt][g] = __builtin_amdgcn_mfma_f32_16x16x32_bf16(
                        af[mt], wf[g][kt], acc[mt][g], 0, 0, 0);
        }

        // gates -> c,h (fp32, per-lane); write h_t into the OTHER panel (or out)
#pragma unroll
        for (int mt = 0; mt < 5; ++mt)
#pragma unroll
            for (int r = 0; r < 4; ++r) {
                float ig = fsigmoid(acc[mt][0][r]);
                float fg = fsigmoid(acc[mt][1][r]);
                float gg = ftanh(acc[mt][2][r]);
                float og = fsigmoid(acc[mt][3][r]);
                float cn = fg * c[mt][r] + ig * gg;
                c[mt][r] = cn;
                float h = og * ftanh(cn);
                int node = mt * 16 + (lane >> 4) * 4 + r;
                if (t < T_WIN - 1) {
                    *(unsigned short*)&Abuf[nxt][node * ASTR + ((colw * 2) ^ ((node & 7) << 4))] = f2bf(h);
                } else {
                    hout[(size_t)(n0 + node) * HID + colw] = h;
                }
            }

        // write prefetched x_{t+1} into the next panel
        if (xactive && t + 1 < T_WIN) {
            ushortx4 b;
            b.x = f2bf(xv.x); b.y = f2bf(xv.y); b.z = f2bf(xv.z); b.w = f2bf(xv.w);
            *(ushortx4*)&Abuf[nxt][xnode * ASTR + xoff] = b;
        }
        __syncthreads();   // panel[nxt] complete; panel[cur] reads done
    }
}

// ---------------- GEMM2: xl = h@Wl^T + bl ; xr = h@Wr^T + br ----------------
__global__ __launch_bounds__(256) void gemm2_kernel(
    const float* __restrict__ h,
    const float* __restrict__ Wl, const float* __restrict__ bl,
    const float* __restrict__ Wr, const float* __restrict__ br,
    float* __restrict__ xl, float* __restrict__ xr)
{
    __shared__ __align__(16) float AsT[128 * 68];  // [k][node], stride 68
    __shared__ __align__(16) float Ws[16 * 260];   // [k][col],  stride 260
    const int tid = threadIdx.x;
    const int bn = blockIdx.x & 3;
    const int bm = blockIdx.x >> 2;
    const int n0 = bm * 64;
    const int j0 = bn * 256;
    const float* W    = (j0 < 512) ? Wl : Wr;
    const float* bias = (j0 < 512) ? bl : br;
    float* out        = (j0 < 512) ? xl : xr;
    const int jb = j0 & 511;
    const int txc = tid & 31;
    const int tyn = tid >> 5;

#pragma unroll
    for (int q = 0; q < 8; ++q) {
        int fi = tid + q * 256;
        int node = fi >> 5, k4 = fi & 31;
        float4 v;
        if (n0 + node < N_NODES) v = *(const float4*)&h[(size_t)(n0 + node) * HID + k4 * 4];
        else { v.x = v.y = v.z = v.w = 0.0f; }
        AsT[(k4 * 4 + 0) * 68 + node] = v.x;
        AsT[(k4 * 4 + 1) * 68 + node] = v.y;
        AsT[(k4 * 4 + 2) * 68 + node] = v.z;
        AsT[(k4 * 4 + 3) * 68 + node] = v.w;
    }

    float b8[8];
#pragma unroll
    for (int ni = 0; ni < 8; ++ni) b8[ni] = bias[jb + txc * 8 + ni];
    float acc[8][8];
#pragma unroll
    for (int mi = 0; mi < 8; ++mi)
#pragma unroll
        for (int ni = 0; ni < 8; ++ni) acc[mi][ni] = b8[ni];

    for (int kc = 0; kc < 8; ++kc) {
        __syncthreads();
#pragma unroll
        for (int q = 0; q < 4; ++q) {
            int idx = tid + q * 256;
            int jj = idx >> 2, kq = idx & 3;
            float4 v = *(const float4*)&W[(size_t)(jb + jj) * HID + kc * 16 + kq * 4];
            Ws[(kq * 4 + 0) * 260 + jj] = v.x;
            Ws[(kq * 4 + 1) * 260 + jj] = v.y;
            Ws[(kq * 4 + 2) * 260 + jj] = v.z;
            Ws[(kq * 4 + 3) * 260 + jj] = v.w;
        }
        __syncthreads();
#pragma unroll
        for (int k = 0; k < 16; ++k) {
            float4 a0 = *(const float4*)&AsT[(kc * 16 + k) * 68 + tyn * 8];
            float4 a1 = *(const float4*)&AsT[(kc * 16 + k) * 68 + tyn * 8 + 4];
            float4 w0 = *(const float4*)&Ws[k * 260 + txc * 8];
            float4 w1 = *(const float4*)&Ws[k * 260 + txc * 8 + 4];
            float av[8] = {a0.x, a0.y, a0.z, a0.w, a1.x, a1.y, a1.z, a1.w};
            float wv[8] = {w0.x, w0.y, w0.z, w0.w, w1.x, w1.y, w1.z, w1.w};
#pragma unroll
            for (int mi = 0; mi < 8; ++mi)
#pragma unroll
                for (int ni = 0; ni < 8; ++ni)
                    acc[mi][ni] = fmaf(av[mi], wv[ni], acc[mi][ni]);
        }
    }

#pragma unroll
    for (int mi = 0; mi < 8; ++mi) {
        int n = n0 + tyn * 8 + mi;
        if (n < N_NODES) {
            float4 s0 = {acc[mi][0], acc[mi][1], acc[mi][2], acc[mi][3]};
            float4 s1 = {acc[mi][4], acc[mi][5], acc[mi][6], acc[mi][7]};
            *(float4*)&out[(size_t)n * G4 + jb + txc * 8]     = s0;
            *(float4*)&out[(size_t)n * G4 + jb + txc * 8 + 4] = s1;
        }
    }
}

// ---------------- edge sort (counting sort by dst) ----------------
__global__ void count_kernel(const int* __restrict__ ei, int* __restrict__ cnt)
{
    int e = blockIdx.x * 256 + threadIdx.x;
    if (e < N_EDGES) {
        int dst = ei[N_EDGES + e];
        if (dst >= 0 && dst < N_NODES) atomicAdd(&cnt[dst], 1);
    }
}

__global__ void scan_kernel(const int* __restrict__ cnt, int* __restrict__ base)
{
    __shared__ int ps[256];
    const int tid = threadIdx.x;
    const int CH = (N_NODES + 255) / 256;
    int s = 0;
    for (int i = 0; i < CH; ++i) {
        int idx = tid * CH + i;
        if (idx < N_NODES) s += cnt[idx];
    }
    ps[tid] = s;
    __syncthreads();
    for (int off = 1; off < 256; off <<= 1) {
        int v = (tid >= off) ? ps[tid - off] : 0;
        __syncthreads();
        ps[tid] += v;
        __syncthreads();
    }
    int run = (tid > 0) ? ps[tid - 1] : 0;
    for (int i = 0; i < CH; ++i) {
        int idx = tid * CH + i;
        if (idx < N_NODES) { base[idx] = run; run += cnt[idx]; }
    }
    if (tid == 255) base[N_NODES] = ps[255];
}

__global__ void scatter_kernel(const int* __restrict__ ei, const int* __restrict__ base,
                               int* __restrict__ cnt2, int* __restrict__ srt)
{
    int e = blockIdx.x * 256 + threadIdx.x;
    if (e < N_EDGES) {
        int dst = ei[N_EDGES + e];
        int src = ei[e];
        if (dst >= 0 && dst < N_NODES) {
            int pos = base[dst] + atomicAdd(&cnt2[dst], 1);
            srt[pos] = src;
        }
    }
}

// ---------------- GATv2 aggregate: one wave per dst, online softmax ----------------
__global__ __launch_bounds__(256) void gat_kernel(
    const float* __restrict__ xl, const float* __restrict__ xr,
    const float* __restrict__ att, const float* __restrict__ gbias,
    const float* __restrict__ Wp, const float* __restrict__ bp,
    const int* __restrict__ base, const int* __restrict__ srt,
    float* __restrict__ out)
{
    const int wave = threadIdx.x >> 6;
    const int lane = threadIdx.x & 63;
    const int dst = blockIdx.x * 4 + wave;
    if (dst >= N_NODES) return;

    float4 xr0 = *(const float4*)&xr[(size_t)dst * G4 + lane * 8];
    float4 xr1 = *(const float4*)&xr[(size_t)dst * G4 + lane * 8 + 4];
    float xrv[8] = {xr0.x, xr0.y, xr0.z, xr0.w, xr1.x, xr1.y, xr1.z, xr1.w};
    float4 at0 = *(const float4*)&att[lane * 8];
    float4 at1 = *(const float4*)&att[lane * 8 + 4];
    float atv[8] = {at0.x, at0.y, at0.z, at0.w, at1.x, at1.y, at1.z, at1.w};

    float m = -INFINITY, d = 0.0f;
    float acc[8];
#pragma unroll
    for (int i = 0; i < 8; ++i) acc[i] = 0.0f;

    const int b0 = base[dst], b1 = base[dst + 1];
    for (int idx = b0; idx <= b1; ++idx) {
        int src = (idx < b1) ? srt[idx] : dst;
        float4 v0 = *(const float4*)&xl[(size_t)src * G4 + lane * 8];
        float4 v1 = *(const float4*)&xl[(size_t)src * G4 + lane * 8 + 4];
        float xv[8] = {v0.x, v0.y, v0.z, v0.w, v1.x, v1.y, v1.z, v1.w};
        float p = 0.0f;
#pragma unroll
        for (int i = 0; i < 8; ++i) {
            float e = xv[i] + xrv[i];
            e = (e > 0.0f) ? e : 0.2f * e;
            p = fmaf(atv[i], e, p);
        }
        p += __shfl_xor(p, 1);
        p += __shfl_xor(p, 2);
        p += __shfl_xor(p, 4);
        p += __shfl_xor(p, 8);
        float mn = fmaxf(m, p);
        float scale = __expf(m - mn);
        float al = __expf(p - mn);
        d = d * scale + al;
#pragma unroll
        for (int i = 0; i < 8; ++i) acc[i] = fmaf(al, xv[i], acc[i] * scale);
        m = mn;
    }

    float inv = 1.0f / d;
    float o[8];
#pragma unroll
    for (int i = 0; i < 8; ++i) o[i] = acc[i] * inv;
#pragma unroll
    for (int i = 0; i < 8; ++i) {
        o[i] += __shfl_xor(o[i], 16);
        o[i] += __shfl_xor(o[i], 32);
    }
    const int c0 = (lane & 15) * 8;
    float psum = 0.0f;
#pragma unroll
    for (int i = 0; i < 8; ++i) {
        float s = 0.25f * o[i] + gbias[c0 + i];
        s = (s > 0.0f) ? s : (__expf(s) - 1.0f);
        psum = fmaf(s, Wp[c0 + i], psum);
    }
    psum += __shfl_xor(psum, 1);
    psum += __shfl_xor(psum, 2);
    psum += __shfl_xor(psum, 4);
    psum += __shfl_xor(psum, 8);
    if (lane == 0) out[dst] = psum + bp[0];
}

// ---------------- launch ----------------
extern "C" void kernel_launch(void* const* d_in, const int* in_sizes, int n_in,
                              void* d_out, int out_size, void* d_ws, size_t ws_size,
                              hipStream_t stream)
{
    const float* x        = (const float*)d_in[0];
    const int* ei         = (const int*)d_in[1];     // int32 per harness contract
    const float* Wih      = (const float*)d_in[2];
    const float* Whh      = (const float*)d_in[3];
    const float* bih      = (const float*)d_in[4];
    const float* bhh      = (const float*)d_in[5];
    const float* Wl       = (const float*)d_in[6];
    const float* bl       = (const float*)d_in[7];
    const float* Wr       = (const float*)d_in[8];
    const float* br       = (const float*)d_in[9];
    const float* att      = (const float*)d_in[10];
    const float* gbias    = (const float*)d_in[11];
    const float* Wp       = (const float*)d_in[12];
    const float* bp       = (const float*)d_in[13];
    float* out            = (float*)d_out;

    float* ws            = (float*)d_ws;
    unsigned short* wpk  = (unsigned short*)(ws + WPK_OFF);
    float* bsc  = ws + BIASC_OFF;
    float* h    = ws + H_OFF;
    float* xl   = ws + XL_OFF;
    float* xr   = ws + XR_OFF;
    int* cnt    = (int*)(ws + CNT_OFF);
    int* cnt2   = (int*)(ws + CNT2_OFF);
    int* base   = (int*)(ws + BASE_OFF);
    int* srt    = (int*)(ws + SRT_OFF);

    hipMemsetAsync(cnt, 0, 2 * N_NODES * sizeof(int), stream);

    pack_w_kernel<<<320, 256, 0, stream>>>(Wih, Whh, bih, bhh, wpk, bsc);
    count_kernel<<<(N_EDGES + 255) / 256, 256, 0, stream>>>(ei, cnt);
    scan_kernel<<<1, 256, 0, stream>>>(cnt, base);
    scatter_kernel<<<(N_EDGES + 255) / 256, 256, 0, stream>>>(ei, base, cnt2, srt);

    lstm_mfma_kernel<<<N_NODES / BMM, 512, 0, stream>>>(x, wpk, bsc, h);
    gemm2_kernel<<<((N_NODES + 63) / 64) * 4, 256, 0, stream>>>(h, Wl, bl, Wr, br, xl, xr);
    gat_kernel<<<(N_NODES + 3) / 4, 256, 0, stream>>>(xl, xr, att, gbias, Wp, bp, base, srt, out);
}

// Round 5
// 606.099 us; speedup vs baseline: 5.5813x; 1.1117x over previous
//
#include <hip/hip_runtime.h>
#include <hip/hip_bf16.h>

#define N_NODES 20000
#define N_EDGES 250000
#define T_WIN   60
#define F_IN    16
#define HID     128
#define G4      512      // 4*HID
#define HEADS   4

// ---------------- ws layout (float offsets) ----------------
#define WPK_OFF    0            // 81920 ushort = 40960 floats (MFMA B-frag packed W)
#define BIASC_OFF  73728        // 512
#define H_OFF      74240        // 20000*128 = 2,560,000
#define XL_OFF     2634240      // 20000*512 = 10,240,000
#define XR_OFF     12874240     // 10,240,000
#define CNT_OFF    23114240     // 20000 ints
#define CNT2_OFF   23134240     // 20000 ints
#define BASE_OFF   23154240     // 20001 ints
#define SRT_OFF    23174241     // 250000 ints

typedef __attribute__((ext_vector_type(8))) short short8;
typedef __attribute__((ext_vector_type(4))) float f32x4;
typedef __attribute__((ext_vector_type(4))) unsigned short ushortx4;

// fast activations: v_rcp_f32 (rel err ~2^-22) instead of IEEE divide
__device__ __forceinline__ float fsigmoid(float x) {
    return __builtin_amdgcn_rcpf(1.0f + __expf(-x));
}
__device__ __forceinline__ float ftanh(float x) {
    return fmaf(2.0f, __builtin_amdgcn_rcpf(1.0f + __expf(-2.0f * x)), -1.0f);
}

__device__ __forceinline__ unsigned short f2bf(float f) {
    unsigned u = __float_as_uint(f);
    u += 0x7FFFu + ((u >> 16) & 1u);   // RNE
    return (unsigned short)(u >> 16);
}

// ---------------- pack W into MFMA B-fragment layout ----------------
// Wpk index = (((g*8+ht)*5+kt)*64 + lane)*8 + i
// element: k = kt*32 + (lane>>4)*8 + i ; col = g*128 + ht*16 + (lane&15)
// B[k][col] = k<128 ? Whh[col][k] : (k<144 ? Wih[col][k-128] : 0)
__global__ void pack_w_kernel(const float* __restrict__ Wih, const float* __restrict__ Whh,
                              const float* __restrict__ bih, const float* __restrict__ bhh,
                              unsigned short* __restrict__ wpk, float* __restrict__ biasc)
{
    int idx = blockIdx.x * 256 + threadIdx.x;
    if (idx < 81920) {
        int i  = idx & 7;
        int l  = (idx >> 3) & 63;
        int r  = idx >> 9;
        int kt = r % 5;
        int gh = r / 5;
        int ht = gh & 7;
        int g  = gh >> 3;
        int k   = kt * 32 + (l >> 4) * 8 + i;
        int col = g * 128 + ht * 16 + (l & 15);
        float v = 0.0f;
        if (k < 128)      v = Whh[col * 128 + k];
        else if (k < 144) v = Wih[col * 16 + (k - 128)];
        wpk[idx] = f2bf(v);
    }
    if (idx < G4) biasc[idx] = bih[idx] + bhh[idx];
}

// ---------------- LSTM: MFMA bf16, 80 nodes/block, double-buffered, 1 barrier/step ----------------
// LDS A-panels: 2 x [80 nodes][384 bytes] (k*2 byte offset, XOR-swizzled by (node&7)<<4)
//   k 0..127 = h (bf16), k 128..143 = x_t (bf16), k 144..159 zero pad
// NOTE: time loop is #pragma unroll 1 ON PURPOSE — unroll 2 doubled live ranges
// and spilled ~96 MB/dispatch to scratch (r4 WRITE_SIZE 135 MB vs 40 MB clean).
#define BMM  80
#define ASTR 384

__global__ __launch_bounds__(512) void lstm_mfma_kernel(
    const float* __restrict__ x, const unsigned short* __restrict__ wpk,
    const float* __restrict__ biasc, float* __restrict__ hout)
{
    __shared__ __align__(16) unsigned char Abuf[2][BMM * ASTR];
    const int tid  = threadIdx.x;
    const int wave = tid >> 6;
    const int lane = tid & 63;
    const int n0   = blockIdx.x * BMM;

    // zero both panels (h0 = 0, pad = 0)
    {
        f32x4 z = {0.0f, 0.0f, 0.0f, 0.0f};
        unsigned char* ab = &Abuf[0][0];
        for (int i = tid; i < 2 * BMM * ASTR / 16; i += 512)
            *(f32x4*)&ab[i * 16] = z;
    }

    // persistent B-fragments: wave w owns hid cols [w*16, w*16+16) for all 4 gates
    short8 wf[4][5];
#pragma unroll
    for (int g = 0; g < 4; ++g)
#pragma unroll
        for (int kt = 0; kt < 5; ++kt)
            wf[g][kt] = *(const short8*)&wpk[((((g * 8 + wave) * 5) + kt) * 64 + lane) * 8];

    float bias[4];
#pragma unroll
    for (int g = 0; g < 4; ++g) bias[g] = biasc[g * 128 + wave * 16 + (lane & 15)];

    float c[5][4];
#pragma unroll
    for (int mt = 0; mt < 5; ++mt)
#pragma unroll
        for (int r = 0; r < 4; ++r) c[mt][r] = 0.0f;

    const int  xnode   = tid >> 2;          // 0..127 (only <80 active)
    const int  xq      = tid & 3;
    const bool xactive = (tid < BMM * 4);   // 320 threads stage x (waves 0-4, uniform)
    const int  xoff    = (256 + xq * 8) ^ ((xnode & 7) << 4);
    const int  colw    = wave * 16 + (lane & 15);
    const float* xptr  = &x[(size_t)(n0 + xnode) * (T_WIN * F_IN) + xq * 4];

    __syncthreads();   // zeroing complete before x_0 staging

    // stage x_0 into panel 0
    if (xactive) {
        float4 v = *(const float4*)xptr;
        ushortx4 b;
        b.x = f2bf(v.x); b.y = f2bf(v.y); b.z = f2bf(v.z); b.w = f2bf(v.w);
        *(ushortx4*)&Abuf[0][xnode * ASTR + xoff] = b;
    }
    __syncthreads();

#pragma unroll 1
    for (int t = 0; t < T_WIN; ++t) {
        const int cur = t & 1;
        const int nxt = cur ^ 1;

        // prefetch x_{t+1} early so HBM latency hides under MFMA
        float4 xv = {0.0f, 0.0f, 0.0f, 0.0f};
        if (xactive && t + 1 < T_WIN) xv = *(const float4*)(xptr + (t + 1) * F_IN);

        f32x4 acc[5][4];
#pragma unroll
        for (int mt = 0; mt < 5; ++mt)
#pragma unroll
            for (int g = 0; g < 4; ++g) {
                f32x4 a = {bias[g], bias[g], bias[g], bias[g]};
                acc[mt][g] = a;
            }

#pragma unroll
        for (int kt = 0; kt < 5; ++kt) {
            short8 af[5];
            const int koff = (kt * 32 + (lane >> 4) * 8) * 2;
#pragma unroll
            for (int mt = 0; mt < 5; ++mt) {
                int row = mt * 16 + (lane & 15);
                af[mt] = *(const short8*)&Abuf[cur][row * ASTR + (koff ^ ((row & 7) << 4))];
            }
#pragma unroll
            for (int mt = 0; mt < 5; ++mt)
#pragma unroll
                for (int g = 0; g < 4; ++g)
                    acc[mt][g] = __builtin_amdgcn_mfma_f32_16x16x32_bf16(
                        af[mt], wf[g][kt], acc[mt][g], 0, 0, 0);
        }

        // gates -> c,h (fp32, per-lane); write h_t into the OTHER panel (or out)
#pragma unroll
        for (int mt = 0; mt < 5; ++mt)
#pragma unroll
            for (int r = 0; r < 4; ++r) {
                float ig = fsigmoid(acc[mt][0][r]);
                float fg = fsigmoid(acc[mt][1][r]);
                float gg = ftanh(acc[mt][2][r]);
                float og = fsigmoid(acc[mt][3][r]);
                float cn = fg * c[mt][r] + ig * gg;
                c[mt][r] = cn;
                float h = og * ftanh(cn);
                int node = mt * 16 + (lane >> 4) * 4 + r;
                if (t < T_WIN - 1) {
                    *(unsigned short*)&Abuf[nxt][node * ASTR + ((colw * 2) ^ ((node & 7) << 4))] = f2bf(h);
                } else {
                    hout[(size_t)(n0 + node) * HID + colw] = h;
                }
            }

        // write prefetched x_{t+1} into the next panel
        if (xactive && t + 1 < T_WIN) {
            ushortx4 b;
            b.x = f2bf(xv.x); b.y = f2bf(xv.y); b.z = f2bf(xv.z); b.w = f2bf(xv.w);
            *(ushortx4*)&Abuf[nxt][xnode * ASTR + xoff] = b;
        }
        __syncthreads();   // panel[nxt] complete; panel[cur] reads done
    }
}

// ---------------- GEMM2: xl = h@Wl^T + bl ; xr = h@Wr^T + br ----------------
__global__ __launch_bounds__(256) void gemm2_kernel(
    const float* __restrict__ h,
    const float* __restrict__ Wl, const float* __restrict__ bl,
    const float* __restrict__ Wr, const float* __restrict__ br,
    float* __restrict__ xl, float* __restrict__ xr)
{
    __shared__ __align__(16) float AsT[128 * 68];  // [k][node], stride 68
    __shared__ __align__(16) float Ws[16 * 260];   // [k][col],  stride 260
    const int tid = threadIdx.x;
    const int bn = blockIdx.x & 3;
    const int bm = blockIdx.x >> 2;
    const int n0 = bm * 64;
    const int j0 = bn * 256;
    const float* W    = (j0 < 512) ? Wl : Wr;
    const float* bias = (j0 < 512) ? bl : br;
    float* out        = (j0 < 512) ? xl : xr;
    const int jb = j0 & 511;
    const int txc = tid & 31;
    const int tyn = tid >> 5;

#pragma unroll
    for (int q = 0; q < 8; ++q) {
        int fi = tid + q * 256;
        int node = fi >> 5, k4 = fi & 31;
        float4 v;
        if (n0 + node < N_NODES) v = *(const float4*)&h[(size_t)(n0 + node) * HID + k4 * 4];
        else { v.x = v.y = v.z = v.w = 0.0f; }
        AsT[(k4 * 4 + 0) * 68 + node] = v.x;
        AsT[(k4 * 4 + 1) * 68 + node] = v.y;
        AsT[(k4 * 4 + 2) * 68 + node] = v.z;
        AsT[(k4 * 4 + 3) * 68 + node] = v.w;
    }

    float b8[8];
#pragma unroll
    for (int ni = 0; ni < 8; ++ni) b8[ni] = bias[jb + txc * 8 + ni];
    float acc[8][8];
#pragma unroll
    for (int mi = 0; mi < 8; ++mi)
#pragma unroll
        for (int ni = 0; ni < 8; ++ni) acc[mi][ni] = b8[ni];

    for (int kc = 0; kc < 8; ++kc) {
        __syncthreads();
#pragma unroll
        for (int q = 0; q < 4; ++q) {
            int idx = tid + q * 256;
            int jj = idx >> 2, kq = idx & 3;
            float4 v = *(const float4*)&W[(size_t)(jb + jj) * HID + kc * 16 + kq * 4];
            Ws[(kq * 4 + 0) * 260 + jj] = v.x;
            Ws[(kq * 4 + 1) * 260 + jj] = v.y;
            Ws[(kq * 4 + 2) * 260 + jj] = v.z;
            Ws[(kq * 4 + 3) * 260 + jj] = v.w;
        }
        __syncthreads();
#pragma unroll
        for (int k = 0; k < 16; ++k) {
            float4 a0 = *(const float4*)&AsT[(kc * 16 + k) * 68 + tyn * 8];
            float4 a1 = *(const float4*)&AsT[(kc * 16 + k) * 68 + tyn * 8 + 4];
            float4 w0 = *(const float4*)&Ws[k * 260 + txc * 8];
            float4 w1 = *(const float4*)&Ws[k * 260 + txc * 8 + 4];
            float av[8] = {a0.x, a0.y, a0.z, a0.w, a1.x, a1.y, a1.z, a1.w};
            float wv[8] = {w0.x, w0.y, w0.z, w0.w, w1.x, w1.y, w1.z, w1.w};
#pragma unroll
            for (int mi = 0; mi < 8; ++mi)
#pragma unroll
                for (int ni = 0; ni < 8; ++ni)
                    acc[mi][ni] = fmaf(av[mi], wv[ni], acc[mi][ni]);
        }
    }

#pragma unroll
    for (int mi = 0; mi < 8; ++mi) {
        int n = n0 + tyn * 8 + mi;
        if (n < N_NODES) {
            float4 s0 = {acc[mi][0], acc[mi][1], acc[mi][2], acc[mi][3]};
            float4 s1 = {acc[mi][4], acc[mi][5], acc[mi][6], acc[mi][7]};
            *(float4*)&out[(size_t)n * G4 + jb + txc * 8]     = s0;
            *(float4*)&out[(size_t)n * G4 + jb + txc * 8 + 4] = s1;
        }
    }
}

// ---------------- edge sort (counting sort by dst) ----------------
__global__ void count_kernel(const int* __restrict__ ei, int* __restrict__ cnt)
{
    int e = blockIdx.x * 256 + threadIdx.x;
    if (e < N_EDGES) {
        int dst = ei[N_EDGES + e];
        if (dst >= 0 && dst < N_NODES) atomicAdd(&cnt[dst], 1);
    }
}

__global__ void scan_kernel(const int* __restrict__ cnt, int* __restrict__ base)
{
    __shared__ int ps[256];
    const int tid = threadIdx.x;
    const int CH = (N_NODES + 255) / 256;
    int s = 0;
    for (int i = 0; i < CH; ++i) {
        int idx = tid * CH + i;
        if (idx < N_NODES) s += cnt[idx];
    }
    ps[tid] = s;
    __syncthreads();
    for (int off = 1; off < 256; off <<= 1) {
        int v = (tid >= off) ? ps[tid - off] : 0;
        __syncthreads();
        ps[tid] += v;
        __syncthreads();
    }
    int run = (tid > 0) ? ps[tid - 1] : 0;
    for (int i = 0; i < CH; ++i) {
        int idx = tid * CH + i;
        if (idx < N_NODES) { base[idx] = run; run += cnt[idx]; }
    }
    if (tid == 255) base[N_NODES] = ps[255];
}

__global__ void scatter_kernel(const int* __restrict__ ei, const int* __restrict__ base,
                               int* __restrict__ cnt2, int* __restrict__ srt)
{
    int e = blockIdx.x * 256 + threadIdx.x;
    if (e < N_EDGES) {
        int dst = ei[N_EDGES + e];
        int src = ei[e];
        if (dst >= 0 && dst < N_NODES) {
            int pos = base[dst] + atomicAdd(&cnt2[dst], 1);
            srt[pos] = src;
        }
    }
}

// ---------------- GATv2 aggregate: one wave per dst, online softmax ----------------
__global__ __launch_bounds__(256) void gat_kernel(
    const float* __restrict__ xl, const float* __restrict__ xr,
    const float* __restrict__ att, const float* __restrict__ gbias,
    const float* __restrict__ Wp, const float* __restrict__ bp,
    const int* __restrict__ base, const int* __restrict__ srt,
    float* __restrict__ out)
{
    const int wave = threadIdx.x >> 6;
    const int lane = threadIdx.x & 63;
    const int dst = blockIdx.x * 4 + wave;
    if (dst >= N_NODES) return;

    float4 xr0 = *(const float4*)&xr[(size_t)dst * G4 + lane * 8];
    float4 xr1 = *(const float4*)&xr[(size_t)dst * G4 + lane * 8 + 4];
    float xrv[8] = {xr0.x, xr0.y, xr0.z, xr0.w, xr1.x, xr1.y, xr1.z, xr1.w};
    float4 at0 = *(const float4*)&att[lane * 8];
    float4 at1 = *(const float4*)&att[lane * 8 + 4];
    float atv[8] = {at0.x, at0.y, at0.z, at0.w, at1.x, at1.y, at1.z, at1.w};

    float m = -INFINITY, d = 0.0f;
    float acc[8];
#pragma unroll
    for (int i = 0; i < 8; ++i) acc[i] = 0.0f;

    const int b0 = base[dst], b1 = base[dst + 1];
    for (int idx = b0; idx <= b1; ++idx) {
        int src = (idx < b1) ? srt[idx] : dst;
        float4 v0 = *(const float4*)&xl[(size_t)src * G4 + lane * 8];
        float4 v1 = *(const float4*)&xl[(size_t)src * G4 + lane * 8 + 4];
        float xv[8] = {v0.x, v0.y, v0.z, v0.w, v1.x, v1.y, v1.z, v1.w};
        float p = 0.0f;
#pragma unroll
        for (int i = 0; i < 8; ++i) {
            float e = xv[i] + xrv[i];
            e = (e > 0.0f) ? e : 0.2f * e;
            p = fmaf(atv[i], e, p);
        }
        p += __shfl_xor(p, 1);
        p += __shfl_xor(p, 2);
        p += __shfl_xor(p, 4);
        p += __shfl_xor(p, 8);
        float mn = fmaxf(m, p);
        float scale = __expf(m - mn);
        float al = __expf(p - mn);
        d = d * scale + al;
#pragma unroll
        for (int i = 0; i < 8; ++i) acc[i] = fmaf(al, xv[i], acc[i] * scale);
        m = mn;
    }

    float inv = 1.0f / d;
    float o[8];
#pragma unroll
    for (int i = 0; i < 8; ++i) o[i] = acc[i] * inv;
#pragma unroll
    for (int i = 0; i < 8; ++i) {
        o[i] += __shfl_xor(o[i], 16);
        o[i] += __shfl_xor(o[i], 32);
    }
    const int c0 = (lane & 15) * 8;
    float psum = 0.0f;
#pragma unroll
    for (int i = 0; i < 8; ++i) {
        float s = 0.25f * o[i] + gbias[c0 + i];
        s = (s > 0.0f) ? s : (__expf(s) - 1.0f);
        psum = fmaf(s, Wp[c0 + i], psum);
    }
    psum += __shfl_xor(psum, 1);
    psum += __shfl_xor(psum, 2);
    psum += __shfl_xor(psum, 4);
    psum += __shfl_xor(psum, 8);
    if (lane == 0) out[dst] = psum + bp[0];
}

// ---------------- launch ----------------
extern "C" void kernel_launch(void* const* d_in, const int* in_sizes, int n_in,
                              void* d_out, int out_size, void* d_ws, size_t ws_size,
                              hipStream_t stream)
{
    const float* x        = (const float*)d_in[0];
    const int* ei         = (const int*)d_in[1];     // int32 per harness contract
    const float* Wih      = (const float*)d_in[2];
    const float* Whh      = (const float*)d_in[3];
    const float* bih      = (const float*)d_in[4];
    const float* bhh      = (const float*)d_in[5];
    const float* Wl       = (const float*)d_in[6];
    const float* bl       = (const float*)d_in[7];
    const float* Wr       = (const float*)d_in[8];
    const float* br       = (const float*)d_in[9];
    const float* att      = (const float*)d_in[10];
    const float* gbias    = (const float*)d_in[11];
    const float* Wp       = (const float*)d_in[12];
    const float* bp       = (const float*)d_in[13];
    float* out            = (float*)d_out;

    float* ws            = (float*)d_ws;
    unsigned short* wpk  = (unsigned short*)(ws + WPK_OFF);
    float* bsc  = ws + BIASC_OFF;
    float* h    = ws + H_OFF;
    float* xl   = ws + XL_OFF;
    float* xr   = ws + XR_OFF;
    int* cnt    = (int*)(ws + CNT_OFF);
    int* cnt2   = (int*)(ws + CNT2_OFF);
    int* base   = (int*)(ws + BASE_OFF);
    int* srt    = (int*)(ws + SRT_OFF);

    hipMemsetAsync(cnt, 0, 2 * N_NODES * sizeof(int), stream);

    pack_w_kernel<<<320, 256, 0, stream>>>(Wih, Whh, bih, bhh, wpk, bsc);
    count_kernel<<<(N_EDGES + 255) / 256, 256, 0, stream>>>(ei, cnt);
    scan_kernel<<<1, 256, 0, stream>>>(cnt, base);
    scatter_kernel<<<(N_EDGES + 255) / 256, 256, 0, stream>>>(ei, base, cnt2, srt);

    lstm_mfma_kernel<<<N_NODES / BMM, 512, 0, stream>>>(x, wpk, bsc, h);
    gemm2_kernel<<<((N_NODES + 63) / 64) * 4, 256, 0, stream>>>(h, Wl, bl, Wr, br, xl, xr);
    gat_kernel<<<(N_NODES + 3) / 4, 256, 0, stream>>>(xl, xr, att, gbias, Wp, bp, base, srt, out);
}

// Round 6
// 409.453 us; speedup vs baseline: 8.2617x; 1.4803x over previous
//
#include <hip/hip_runtime.h>
#include <hip/hip_bf16.h>

#define N_NODES 20000
#define N_EDGES 250000
#define T_WIN   60
#define F_IN    16
#define HID     128
#define G4      512      // 4*HID
#define HEADS   4

// ---------------- ws layout (float offsets) ----------------
#define WPK_OFF    0            // 81920 ushort (LSTM W B-frags)
#define BIASC_OFF  40960        // 512
#define WPK2_OFF   41472        // 131072 ushort (GAT-lin W B-frags) = 65536 floats
#define BIASC2_OFF 107008       // 1024
#define H_OFF      108032       // 20000*128 ushort (bf16 h) = 1,280,000 floats
#define XL_OFF     1388032      // 20000*512 ushort = 5,120,000 floats
#define XR_OFF     6508032      // 20000*512 ushort
#define CNT_OFF    11628032     // 20000 ints
#define CNT2_OFF   11648032     // 20000 ints
#define BASE_OFF   11668032     // 20001 ints
#define SRT_OFF    11688033     // 250000 ints

typedef __attribute__((ext_vector_type(8))) short short8;
typedef __attribute__((ext_vector_type(8))) unsigned short ushort8;
typedef __attribute__((ext_vector_type(4))) float f32x4;
typedef __attribute__((ext_vector_type(4))) unsigned short ushortx4;

// fast activations: v_rcp_f32 (rel err ~2^-22) instead of IEEE divide
__device__ __forceinline__ float fsigmoid(float x) {
    return __builtin_amdgcn_rcpf(1.0f + __expf(-x));
}
__device__ __forceinline__ float ftanh(float x) {
    return fmaf(2.0f, __builtin_amdgcn_rcpf(1.0f + __expf(-2.0f * x)), -1.0f);
}

__device__ __forceinline__ unsigned short f2bf(float f) {
    unsigned u = __float_as_uint(f);
    u += 0x7FFFu + ((u >> 16) & 1u);   // RNE
    return (unsigned short)(u >> 16);
}
__device__ __forceinline__ float bf2f(unsigned short u) {
    return __uint_as_float((unsigned)u << 16);
}
// pack 2 fp32 -> 2 bf16 (RNE) in one instruction
__device__ __forceinline__ unsigned cvt_pk_bf16(float a, float b) {
    unsigned r;
    asm("v_cvt_pk_bf16_f32 %0, %1, %2" : "=v"(r) : "v"(a), "v"(b));
    return r;
}

// ---------------- pack LSTM W into MFMA B-fragment layout ----------------
// Wpk index = (((g*8+ht)*5+kt)*64 + lane)*8 + i
// element: k = kt*32 + (lane>>4)*8 + i ; col = g*128 + ht*16 + (lane&15)
__global__ void pack_w_kernel(const float* __restrict__ Wih, const float* __restrict__ Whh,
                              const float* __restrict__ bih, const float* __restrict__ bhh,
                              unsigned short* __restrict__ wpk, float* __restrict__ biasc)
{
    int idx = blockIdx.x * 256 + threadIdx.x;
    if (idx < 81920) {
        int i  = idx & 7;
        int l  = (idx >> 3) & 63;
        int r  = idx >> 9;
        int kt = r % 5;
        int gh = r / 5;
        int ht = gh & 7;
        int g  = gh >> 3;
        int k   = kt * 32 + (l >> 4) * 8 + i;
        int col = g * 128 + ht * 16 + (l & 15);
        float v = 0.0f;
        if (k < 128)      v = Whh[col * 128 + k];
        else if (k < 144) v = Wih[col * 16 + (k - 128)];
        wpk[idx] = f2bf(v);
    }
    if (idx < G4) biasc[idx] = bih[idx] + bhh[idx];
}

// ---------------- pack GAT lin W (Wl|Wr -> [128 k][1024 cols]) into B-frags ----------------
// wpk2 idx = ((ht*4+kt)*64 + lane)*8 + i ; k = kt*32+(lane>>4)*8+i ; col = ht*16+(lane&15)
__global__ void pack_w2_kernel(const float* __restrict__ Wl, const float* __restrict__ bl,
                               const float* __restrict__ Wr, const float* __restrict__ br,
                               unsigned short* __restrict__ wpk2, float* __restrict__ biasc2)
{
    int idx = blockIdx.x * 256 + threadIdx.x;
    if (idx < 131072) {
        int i  = idx & 7;
        int l  = (idx >> 3) & 63;
        int f  = idx >> 9;       // ht*4 + kt
        int kt = f & 3;
        int ht = f >> 2;
        int k   = kt * 32 + (l >> 4) * 8 + i;
        int col = ht * 16 + (l & 15);
        float v = (col < 512) ? Wl[col * 128 + k] : Wr[(col - 512) * 128 + k];
        wpk2[idx] = f2bf(v);
    }
    if (idx < 1024) biasc2[idx] = (idx < 512) ? bl[idx] : br[idx - 512];
}

// ---------------- LSTM: MFMA bf16, 80 nodes/block, double-buffered, 1 barrier/step ----------------
// NOTE: time loop is unroll 1 ON PURPOSE (r4: unroll 2 spilled ~96 MB to scratch).
#define BMM  80
#define ASTR 384

__global__ __launch_bounds__(512) void lstm_mfma_kernel(
    const float* __restrict__ x, const unsigned short* __restrict__ wpk,
    const float* __restrict__ biasc, unsigned short* __restrict__ hout)
{
    __shared__ __align__(16) unsigned char Abuf[2][BMM * ASTR];
    const int tid  = threadIdx.x;
    const int wave = tid >> 6;
    const int lane = tid & 63;
    const int n0   = blockIdx.x * BMM;

    {
        f32x4 z = {0.0f, 0.0f, 0.0f, 0.0f};
        unsigned char* ab = &Abuf[0][0];
        for (int i = tid; i < 2 * BMM * ASTR / 16; i += 512)
            *(f32x4*)&ab[i * 16] = z;
    }

    // persistent B-fragments: wave w owns hid cols [w*16, w*16+16) for all 4 gates
    short8 wf[4][5];
#pragma unroll
    for (int g = 0; g < 4; ++g)
#pragma unroll
        for (int kt = 0; kt < 5; ++kt)
            wf[g][kt] = *(const short8*)&wpk[((((g * 8 + wave) * 5) + kt) * 64 + lane) * 8];

    float bias[4];
#pragma unroll
    for (int g = 0; g < 4; ++g) bias[g] = biasc[g * 128 + wave * 16 + (lane & 15)];

    float c[5][4];
#pragma unroll
    for (int mt = 0; mt < 5; ++mt)
#pragma unroll
        for (int r = 0; r < 4; ++r) c[mt][r] = 0.0f;

    const int  xnode   = tid >> 2;
    const int  xq      = tid & 3;
    const bool xactive = (tid < BMM * 4);
    const int  xoff    = (256 + xq * 8) ^ ((xnode & 7) << 4);
    const int  colw    = wave * 16 + (lane & 15);
    const float* xptr  = &x[(size_t)(n0 + xnode) * (T_WIN * F_IN) + xq * 4];

    __syncthreads();

    if (xactive) {
        float4 v = *(const float4*)xptr;
        ushortx4 b;
        b.x = f2bf(v.x); b.y = f2bf(v.y); b.z = f2bf(v.z); b.w = f2bf(v.w);
        *(ushortx4*)&Abuf[0][xnode * ASTR + xoff] = b;
    }
    __syncthreads();

#pragma unroll 1
    for (int t = 0; t < T_WIN; ++t) {
        const int cur = t & 1;
        const int nxt = cur ^ 1;

        float4 xv = {0.0f, 0.0f, 0.0f, 0.0f};
        if (xactive && t + 1 < T_WIN) xv = *(const float4*)(xptr + (t + 1) * F_IN);

        // per-mt: ds_read -> 20 MFMA -> activation (act(mt) overlaps MFMA(mt+1))
#pragma unroll
        for (int mt = 0; mt < 5; ++mt) {
            const int row = mt * 16 + (lane & 15);
            const int rsw = (row & 7) << 4;
            short8 af[5];
#pragma unroll
            for (int kt = 0; kt < 5; ++kt)
                af[kt] = *(const short8*)&Abuf[cur][row * ASTR + ((kt * 64 + (lane >> 4) * 16) ^ rsw)];

            f32x4 ag[4];
#pragma unroll
            for (int g = 0; g < 4; ++g) {
                f32x4 a = {bias[g], bias[g], bias[g], bias[g]};
                ag[g] = a;
            }
#pragma unroll
            for (int kt = 0; kt < 5; ++kt)
#pragma unroll
                for (int g = 0; g < 4; ++g)
                    ag[g] = __builtin_amdgcn_mfma_f32_16x16x32_bf16(af[kt], wf[g][kt], ag[g], 0, 0, 0);

#pragma unroll
            for (int rp = 0; rp < 2; ++rp) {
                float hh[2];
#pragma unroll
                for (int r2 = 0; r2 < 2; ++r2) {
                    const int r = rp * 2 + r2;
                    float ig = fsigmoid(ag[0][r]);
                    float fg = fsigmoid(ag[1][r]);
                    float gg = ftanh(ag[2][r]);
                    float og = fsigmoid(ag[3][r]);
                    float cn = fg * c[mt][r] + ig * gg;
                    c[mt][r] = cn;
                    hh[r2] = og * ftanh(cn);
                }
                const unsigned pk = cvt_pk_bf16(hh[0], hh[1]);
                const int node0 = mt * 16 + (lane >> 4) * 4 + rp * 2;
                const int node1 = node0 + 1;
                if (t < T_WIN - 1) {
                    *(unsigned short*)&Abuf[nxt][node0 * ASTR + ((colw * 2) ^ ((node0 & 7) << 4))] =
                        (unsigned short)pk;
                    *(unsigned short*)&Abuf[nxt][node1 * ASTR + ((colw * 2) ^ ((node1 & 7) << 4))] =
                        (unsigned short)(pk >> 16);
                } else {
                    hout[(size_t)(n0 + node0) * HID + colw] = (unsigned short)pk;
                    hout[(size_t)(n0 + node1) * HID + colw] = (unsigned short)(pk >> 16);
                }
            }
        }

        if (xactive && t + 1 < T_WIN) {
            ushortx4 b;
            b.x = f2bf(xv.x); b.y = f2bf(xv.y); b.z = f2bf(xv.z); b.w = f2bf(xv.w);
            *(ushortx4*)&Abuf[nxt][xnode * ASTR + xoff] = b;
        }
        __syncthreads();
    }
}

// ---------------- GEMM2 (MFMA): [xl|xr] = h @ [Wl|Wr]^T + bias, bf16 in/out ----------------
#define G2_BM 64
__global__ __launch_bounds__(256) void gemm2_mfma_kernel(
    const unsigned short* __restrict__ hbf,   // [20000][128] bf16
    const unsigned short* __restrict__ wpk2,  // packed B-frags
    const float* __restrict__ biasc2,         // [1024]
    unsigned short* __restrict__ xl, unsigned short* __restrict__ xr)
{
    __shared__ __align__(16) unsigned char Hs[G2_BM * 256];  // [64 rows][128 bf16], XOR-swizzled
    const int tid  = threadIdx.x;
    const int wave = tid >> 6;
    const int lane = tid & 63;
    const int mb = blockIdx.x >> 2;
    const int nb = blockIdx.x & 3;     // 4 col-blocks of 256 (0,1 -> xl; 2,3 -> xr)
    const int n0 = mb * G2_BM;

    // stage h tile (bf16) with XOR swizzle
#pragma unroll
    for (int q = 0; q < 4; ++q) {
        int fi = tid + q * 256;            // 16B unit over [64][16]
        int node = fi >> 4;
        int kb = (fi & 15) * 16;           // byte offset in row
        ushort8 v = {0, 0, 0, 0, 0, 0, 0, 0};
        if (n0 + node < N_NODES) v = *(const ushort8*)&hbf[(size_t)(n0 + node) * HID + kb / 2];
        *(ushort8*)&Hs[node * 256 + (kb ^ ((node & 7) << 4))] = v;
    }
    __syncthreads();

    const int colt0 = nb * 16 + wave * 4;  // global col-tile base (16-col tiles)
    float bias4[4];
#pragma unroll
    for (int ct = 0; ct < 4; ++ct)
        bias4[ct] = biasc2[(colt0 + ct) * 16 + (lane & 15)];

    f32x4 acc[4][4];
#pragma unroll
    for (int mt = 0; mt < 4; ++mt)
#pragma unroll
        for (int ct = 0; ct < 4; ++ct) {
            f32x4 a = {bias4[ct], bias4[ct], bias4[ct], bias4[ct]};
            acc[mt][ct] = a;
        }

#pragma unroll
    for (int kt = 0; kt < 4; ++kt) {
        short8 wf[4];
#pragma unroll
        for (int ct = 0; ct < 4; ++ct)
            wf[ct] = *(const short8*)&wpk2[(((colt0 + ct) * 4 + kt) * 64 + lane) * 8];
        short8 af[4];
        const int kbyte = kt * 64 + (lane >> 4) * 16;
#pragma unroll
        for (int mt = 0; mt < 4; ++mt) {
            int row = mt * 16 + (lane & 15);
            af[mt] = *(const short8*)&Hs[row * 256 + (kbyte ^ ((row & 7) << 4))];
        }
#pragma unroll
        for (int mt = 0; mt < 4; ++mt)
#pragma unroll
            for (int ct = 0; ct < 4; ++ct)
                acc[mt][ct] = __builtin_amdgcn_mfma_f32_16x16x32_bf16(af[mt], wf[ct], acc[mt][ct], 0, 0, 0);
    }

    unsigned short* outp = (nb < 2) ? xl : xr;
    const int lcol = (nb & 1) * 256 + wave * 64 + (lane & 15);
#pragma unroll
    for (int mt = 0; mt < 4; ++mt)
#pragma unroll
        for (int ct = 0; ct < 4; ++ct)
#pragma unroll
            for (int r = 0; r < 4; ++r) {
                int row = n0 + mt * 16 + (lane >> 4) * 4 + r;
                if (row < N_NODES)
                    outp[(size_t)row * G4 + lcol + ct * 16] = f2bf(acc[mt][ct][r]);
            }
}

// ---------------- edge sort (counting sort by dst) ----------------
__global__ void count_kernel(const int* __restrict__ ei, int* __restrict__ cnt)
{
    int e = blockIdx.x * 256 + threadIdx.x;
    if (e < N_EDGES) {
        int dst = ei[N_EDGES + e];
        if (dst >= 0 && dst < N_NODES) atomicAdd(&cnt[dst], 1);
    }
}

__global__ void scan_kernel(const int* __restrict__ cnt, int* __restrict__ base)
{
    __shared__ int ps[256];
    const int tid = threadIdx.x;
    const int CH = (N_NODES + 255) / 256;
    int s = 0;
    for (int i = 0; i < CH; ++i) {
        int idx = tid * CH + i;
        if (idx < N_NODES) s += cnt[idx];
    }
    ps[tid] = s;
    __syncthreads();
    for (int off = 1; off < 256; off <<= 1) {
        int v = (tid >= off) ? ps[tid - off] : 0;
        __syncthreads();
        ps[tid] += v;
        __syncthreads();
    }
    int run = (tid > 0) ? ps[tid - 1] : 0;
    for (int i = 0; i < CH; ++i) {
        int idx = tid * CH + i;
        if (idx < N_NODES) { base[idx] = run; run += cnt[idx]; }
    }
    if (tid == 255) base[N_NODES] = ps[255];
}

__global__ void scatter_kernel(const int* __restrict__ ei, const int* __restrict__ base,
                               int* __restrict__ cnt2, int* __restrict__ srt)
{
    int e = blockIdx.x * 256 + threadIdx.x;
    if (e < N_EDGES) {
        int dst = ei[N_EDGES + e];
        int src = ei[e];
        if (dst >= 0 && dst < N_NODES) {
            int pos = base[dst] + atomicAdd(&cnt2[dst], 1);
            srt[pos] = src;
        }
    }
}

// ---------------- GATv2 aggregate: one wave per dst, online softmax (bf16 xl/xr) ----------------
__global__ __launch_bounds__(256) void gat_kernel(
    const unsigned short* __restrict__ xl, const unsigned short* __restrict__ xr,
    const float* __restrict__ att, const float* __restrict__ gbias,
    const float* __restrict__ Wp, const float* __restrict__ bp,
    const int* __restrict__ base, const int* __restrict__ srt,
    float* __restrict__ out)
{
    const int wave = threadIdx.x >> 6;
    const int lane = threadIdx.x & 63;
    const int dst = blockIdx.x * 4 + wave;
    if (dst >= N_NODES) return;

    ushort8 xr8 = *(const ushort8*)&xr[(size_t)dst * G4 + lane * 8];
    float xrv[8];
#pragma unroll
    for (int i = 0; i < 8; ++i) xrv[i] = bf2f(xr8[i]);
    float4 at0 = *(const float4*)&att[lane * 8];
    float4 at1 = *(const float4*)&att[lane * 8 + 4];
    float atv[8] = {at0.x, at0.y, at0.z, at0.w, at1.x, at1.y, at1.z, at1.w};

    float m = -INFINITY, d = 0.0f;
    float acc[8];
#pragma unroll
    for (int i = 0; i < 8; ++i) acc[i] = 0.0f;

    const int b0 = base[dst], b1 = base[dst + 1];
    for (int idx = b0; idx <= b1; ++idx) {
        int src = (idx < b1) ? srt[idx] : dst;
        ushort8 v8 = *(const ushort8*)&xl[(size_t)src * G4 + lane * 8];
        float xv[8];
#pragma unroll
        for (int i = 0; i < 8; ++i) xv[i] = bf2f(v8[i]);
        float p = 0.0f;
#pragma unroll
        for (int i = 0; i < 8; ++i) {
            float e = xv[i] + xrv[i];
            e = (e > 0.0f) ? e : 0.2f * e;
            p = fmaf(atv[i], e, p);
        }
        p += __shfl_xor(p, 1);
        p += __shfl_xor(p, 2);
        p += __shfl_xor(p, 4);
        p += __shfl_xor(p, 8);
        float mn = fmaxf(m, p);
        float scale = __expf(m - mn);
        float al = __expf(p - mn);
        d = d * scale + al;
#pragma unroll
        for (int i = 0; i < 8; ++i) acc[i] = fmaf(al, xv[i], acc[i] * scale);
        m = mn;
    }

    float inv = 1.0f / d;
    float o[8];
#pragma unroll
    for (int i = 0; i < 8; ++i) o[i] = acc[i] * inv;
#pragma unroll
    for (int i = 0; i < 8; ++i) {
        o[i] += __shfl_xor(o[i], 16);
        o[i] += __shfl_xor(o[i], 32);
    }
    const int c0 = (lane & 15) * 8;
    float psum = 0.0f;
#pragma unroll
    for (int i = 0; i < 8; ++i) {
        float s = 0.25f * o[i] + gbias[c0 + i];
        s = (s > 0.0f) ? s : (__expf(s) - 1.0f);
        psum = fmaf(s, Wp[c0 + i], psum);
    }
    psum += __shfl_xor(psum, 1);
    psum += __shfl_xor(psum, 2);
    psum += __shfl_xor(psum, 4);
    psum += __shfl_xor(psum, 8);
    if (lane == 0) out[dst] = psum + bp[0];
}

// ---------------- launch ----------------
extern "C" void kernel_launch(void* const* d_in, const int* in_sizes, int n_in,
                              void* d_out, int out_size, void* d_ws, size_t ws_size,
                              hipStream_t stream)
{
    const float* x        = (const float*)d_in[0];
    const int* ei         = (const int*)d_in[1];     // int32 per harness contract
    const float* Wih      = (const float*)d_in[2];
    const float* Whh      = (const float*)d_in[3];
    const float* bih      = (const float*)d_in[4];
    const float* bhh      = (const float*)d_in[5];
    const float* Wl       = (const float*)d_in[6];
    const float* bl       = (const float*)d_in[7];
    const float* Wr       = (const float*)d_in[8];
    const float* br       = (const float*)d_in[9];
    const float* att      = (const float*)d_in[10];
    const float* gbias    = (const float*)d_in[11];
    const float* Wp       = (const float*)d_in[12];
    const float* bp       = (const float*)d_in[13];
    float* out            = (float*)d_out;

    float* ws             = (float*)d_ws;
    unsigned short* wpk   = (unsigned short*)(ws + WPK_OFF);
    float* bsc            = ws + BIASC_OFF;
    unsigned short* wpk2  = (unsigned short*)(ws + WPK2_OFF);
    float* bsc2           = ws + BIASC2_OFF;
    unsigned short* h     = (unsigned short*)(ws + H_OFF);
    unsigned short* xlb   = (unsigned short*)(ws + XL_OFF);
    unsigned short* xrb   = (unsigned short*)(ws + XR_OFF);
    int* cnt    = (int*)(ws + CNT_OFF);
    int* cnt2   = (int*)(ws + CNT2_OFF);
    int* base   = (int*)(ws + BASE_OFF);
    int* srt    = (int*)(ws + SRT_OFF);

    hipMemsetAsync(cnt, 0, 2 * N_NODES * sizeof(int), stream);

    pack_w_kernel<<<320, 256, 0, stream>>>(Wih, Whh, bih, bhh, wpk, bsc);
    pack_w2_kernel<<<512, 256, 0, stream>>>(Wl, bl, Wr, br, wpk2, bsc2);
    count_kernel<<<(N_EDGES + 255) / 256, 256, 0, stream>>>(ei, cnt);
    scan_kernel<<<1, 256, 0, stream>>>(cnt, base);
    scatter_kernel<<<(N_EDGES + 255) / 256, 256, 0, stream>>>(ei, base, cnt2, srt);

    lstm_mfma_kernel<<<N_NODES / BMM, 512, 0, stream>>>(x, wpk, bsc, h);
    gemm2_mfma_kernel<<<((N_NODES + G2_BM - 1) / G2_BM) * 4, 256, 0, stream>>>(h, wpk2, bsc2, xlb, xrb);
    gat_kernel<<<(N_NODES + 3) / 4, 256, 0, stream>>>(xlb, xrb, att, gbias, Wp, bp, base, srt, out);
}